// Round 13
// baseline (203.600 us; speedup 1.0000x reference)
//
#include <hip/hip_runtime.h>
#include <hip/hip_bf16.h>
#include <math.h>

// Problem constants (fixed by harness)
#define T_LEN 2048
#define EMB   2048
#define NH    32
#define HD    64
#define HALF  32

typedef __attribute__((ext_vector_type(8))) short short8v;    // 8 bf16
typedef __attribute__((ext_vector_type(4))) float floatx4;    // 16x16 C/D
typedef __attribute__((ext_vector_type(16))) float floatx16;  // 32x32 C/D

// async global->LDS, 16B per lane. LDS dest is wave-uniform base + lane*16.
__device__ inline void gload_lds16(const void* g, void* l) {
    __builtin_amdgcn_global_load_lds(
        (const __attribute__((address_space(1))) unsigned int*)g,
        (__attribute__((address_space(3))) unsigned int*)l,
        16, 0, 0);
}

__device__ inline ushort f2bf(float x) {
    union { float f; unsigned u; } c; c.f = x;
    const unsigned r = c.u + 0x7FFFu + ((c.u >> 16) & 1u);  // RNE
    return (ushort)(r >> 16);
}

// raw barrier with compiler memory fences (NO vmcnt drain, unlike __syncthreads)
#define BARRIER() do { asm volatile("" ::: "memory"); \
    __builtin_amdgcn_s_barrier(); asm volatile("" ::: "memory"); } while (0)
#define VMW8() asm volatile("s_waitcnt vmcnt(8)" ::: "memory")
#define VMW0() asm volatile("s_waitcnt vmcnt(0)" ::: "memory")

// ---------------------------------------------------------------------------
// Fused: fp32->bf16 conversion of all 7 tensors (blocks 0..14335) + rotary
// coefficient tables (blocks 14336..14591). Q table folds xscale *
// scale_attention * HD^-0.5 * log2(e); K table = 1/xscale.
// ---------------------------------------------------------------------------
__global__ __launch_bounds__(256) void conv_all(
    const float* __restrict__ s0, const float* __restrict__ s1,
    const float* __restrict__ s2, const float* __restrict__ s3,
    const float* __restrict__ s4, const float* __restrict__ s5,
    const float* __restrict__ s6, ushort* __restrict__ dst,
    const float* __restrict__ sinp, const float* __restrict__ cosp,
    const float* __restrict__ xscale,
    float2* __restrict__ qt, float2* __restrict__ kt)
{
    if (blockIdx.x >= 14336) {
        const int idx = (blockIdx.x - 14336) * 256 + threadIdx.x;  // 65536
        const int t = idx >> 5;
        const float s = sinp[idx], c = cosp[idx], xs = xscale[idx];
        float sa = 1.f;
        if (t >= 2) {
            const float lv = __logf((float)t) * 0.14426950408889634f; // /ln(1024)
            sa = lv > 1.f ? lv : 1.f;
        }
        const float qs = xs * sa * 0.125f * 1.4426950408889634f;  // * log2(e)
        qt[idx] = make_float2(c * qs, s * qs);
        const float ks = 1.f / xs;
        kt[idx] = make_float2(c * ks, s * ks);
        return;
    }
    const int idx = blockIdx.x * 256 + threadIdx.x;   // 7 * 2^19 threads
    const int t = idx >> 19;
    const int r = (idx & 524287) * 8;
    const float* in = t == 0 ? s0 : t == 1 ? s1 : t == 2 ? s2 : t == 3 ? s3
                    : t == 4 ? s4 : t == 5 ? s5 : s6;
    const float4 v0 = *reinterpret_cast<const float4*>(&in[r]);
    const float4 v1 = *reinterpret_cast<const float4*>(&in[r + 4]);
    ushort o[8];
    o[0] = f2bf(v0.x); o[1] = f2bf(v0.y); o[2] = f2bf(v0.z); o[3] = f2bf(v0.w);
    o[4] = f2bf(v1.x); o[5] = f2bf(v1.y); o[6] = f2bf(v1.z); o[7] = f2bf(v1.w);
    *reinterpret_cast<uint4*>(&dst[(size_t)t * 4194304 + r]) =
        *reinterpret_cast<const uint4*>(o);
}

// ---------------------------------------------------------------------------
// QKV projection, 256x256-tile 8-phase GEMM, 3-slot-A pipeline (measured
// plateau ~70.6 µs; kept). ALL slot indices compile-time (round-7 lesson).
// ---------------------------------------------------------------------------
#define QBM 256
#define QBN 256

#define STAGE_A3(tau, h, slot) do {                                            \
    const int _tc = (tau) * 64;                                                \
    _Pragma("unroll") for (int _i = 0; _i < 2; ++_i) {                         \
        gload_lds16(&Ap[(size_t)(bm + (h) * 128 + wid * 16 + _i * 8 + rl) * 2048 + _tc + csw], \
                    &lds[(slot) * 16384 + (h) * 8192 + (wid * 16 + _i * 8) * 64]); \
    } } while (0)

#define STAGE_B2(tau, h, slot) do {                                            \
    const int _tc = (tau) * 64;                                                \
    _Pragma("unroll") for (int _i = 0; _i < 2; ++_i) {                         \
        gload_lds16(&Bp[(size_t)(bn + (h) * 128 + wid * 16 + _i * 8 + rl) * 2048 + _tc + csw], \
                    &lds[49152 + (slot) * 16384 + (h) * 8192 + (wid * 16 + _i * 8) * 64]); \
    } } while (0)

#define PH(sa_, sb_, mp, VMWSTMT, ...) do {                                    \
    if ((mp) == 0) {                                                           \
        _Pragma("unroll") for (int n = 0; n < 4; ++n) {                        \
            bf[n][0] = ldB(sb_, n, 0);                                         \
            bf[n][1] = ldB(sb_, n, 1);                                         \
        }                                                                      \
    }                                                                          \
    af[0][0] = ldA(sa_, (mp) * 2, 0);     af[0][1] = ldA(sa_, (mp) * 2, 1);    \
    af[1][0] = ldA(sa_, (mp) * 2 + 1, 0); af[1][1] = ldA(sa_, (mp) * 2 + 1, 1);\
    __VA_ARGS__;                                                               \
    BARRIER();                                                                 \
    __builtin_amdgcn_s_setprio(1);                                             \
    _Pragma("unroll") for (int mm = 0; mm < 2; ++mm)                           \
    _Pragma("unroll") for (int n = 0; n < 4; ++n)                              \
    _Pragma("unroll") for (int kk = 0; kk < 2; ++kk)                           \
        acc[(mp) * 2 + mm][n] = __builtin_amdgcn_mfma_f32_16x16x32_bf16(       \
            af[mm][kk], bf[n][kk], acc[(mp) * 2 + mm][n], 0, 0, 0);            \
    __builtin_amdgcn_s_setprio(0);                                             \
    VMWSTMT;                                                                   \
    BARRIER();                                                                 \
} while (0)

#define TILE6(sa, sb, sa2, tau2, LASTVMW) do {                                 \
    PH(sa, sb, 0, (void)0, STAGE_A3(tau2, 0, sa2));                            \
    PH(sa, sb, 1, (void)0, STAGE_A3(tau2, 1, sa2));                            \
    PH(sa, sb, 2, (void)0, STAGE_B2(tau2, 0, sb));                             \
    PH(sa, sb, 3, LASTVMW, STAGE_B2(tau2, 1, sb));                             \
} while (0)

__global__ __launch_bounds__(512, 2) void gemm_qkv8(
    const ushort* __restrict__ Astack,   // [Aq|Ak|Av] bf16, each [2048][2048]
    const ushort* __restrict__ Wstack,   // [Wq|Wk|Wv] bf16, each [2048][2048]
    const float* __restrict__ bq, const float* __restrict__ bk,
    const float* __restrict__ bv,
    ushort* __restrict__ outQ, ushort* __restrict__ outK,
    ushort* __restrict__ outVt,
    const float2* __restrict__ qtab, const float2* __restrict__ ktab)
{
    __shared__ ushort lds[81920];   // 160 KiB: A 3x32KB | B 2x32KB
    const int tid  = threadIdx.x;
    const int lane = tid & 63;
    const int wid  = tid >> 6;      // 0..7

    const int b   = blockIdx.x + blockIdx.y * 24;  // 0..191
    const int xcd = b & 7;
    const int idx = b >> 3;                        // 0..23
    const int bx  = xcd * 3 + (idx >> 3);          // 0..23 col-panel
    const int by  = idx & 7;                       // 0..7  row-panel
    const int which = bx >> 3;                     // 0=Q 1=K 2=V
    const int bn  = (bx & 7) * QBN;
    const int bm  = by * QBM;
    const ushort* Ap = Astack + (size_t)which * 4194304;
    const ushort* Bp = Wstack + (size_t)which * 4194304;

    const int rl  = lane >> 3;
    const int csw = (((lane & 7) ^ ((lane >> 3) & 7)) * 8);
    const int lm  = lane & 15;
    const int lg  = lane >> 4;
    const char* ldsb = reinterpret_cast<const char*>(lds);

    auto ldA = [&](int slot, int m, int kk) -> short8v {
        const int row = m * 16 + lm;
        const int off = (slot * 16384 + (wid >> 2) * 8192) * 2 + row * 128
                      + (((kk * 4 + lg) ^ (row & 7)) * 16);
        return *reinterpret_cast<const short8v*>(ldsb + off);
    };
    auto ldB = [&](int slot, int n, int kk) -> short8v {
        const int row = (wid & 1) * 64 + n * 16 + lm;
        const int off = (49152 + slot * 16384 + ((wid & 3) >> 1) * 8192) * 2
                      + row * 128 + (((kk * 4 + lg) ^ (row & 7)) * 16);
        return *reinterpret_cast<const short8v*>(ldsb + off);
    };

    floatx4 acc[8][4] = {};
    short8v bf[4][2];
    short8v af[2][2];

    STAGE_A3(0, 0, 0); STAGE_A3(0, 1, 0);
    STAGE_B2(0, 0, 0); STAGE_B2(0, 1, 0);
    STAGE_A3(1, 0, 1); STAGE_A3(1, 1, 1);
    STAGE_B2(1, 0, 1); STAGE_B2(1, 1, 1);
    VMW8();
    BARRIER();

    for (int i = 0; i < 5; ++i) {
        const int t = 6 * i;
        TILE6(0, 0, 2, t + 2, VMW8());
        TILE6(1, 1, 0, t + 3, VMW8());
        TILE6(2, 0, 1, t + 4, VMW8());
        TILE6(0, 1, 2, t + 5, VMW8());
        TILE6(1, 0, 0, t + 6, VMW8());
        TILE6(2, 1, 1, t + 7, VMW8());
    }
    PH(0, 0, 0, (void)0, (void)0);
    PH(0, 0, 1, (void)0, (void)0);
    PH(0, 0, 2, (void)0, (void)0);
    PH(0, 0, 3, VMW0(),  (void)0);
    PH(1, 1, 0, (void)0, (void)0);
    PH(1, 1, 1, (void)0, (void)0);
    PH(1, 1, 2, (void)0, (void)0);
    PH(1, 1, 3, (void)0, (void)0);

    const float* bias = which == 0 ? bq : which == 1 ? bk : bv;
    const float2* tbl = which == 0 ? qtab : ktab;
    #pragma unroll
    for (int m = 0; m < 8; ++m) {
        #pragma unroll
        for (int n = 0; n < 4; ++n) {
            const int col = bn + (wid & 3) * 64 + n * 16 + lm;
            const float bz = bias[col];
            const int row0 = bm + (wid >> 2) * 128 + m * 16 + lg * 4;
            if (which == 2) {
                ushort o4[4];
                #pragma unroll
                for (int j = 0; j < 4; ++j)
                    o4[j] = f2bf(acc[m][n][j] + bz);
                *reinterpret_cast<uint2*>(&outVt[(size_t)col * T_LEN + row0]) =
                    *reinterpret_cast<const uint2*>(o4);
            } else {
                ushort* O = which == 0 ? outQ : outK;
                const int p = (col & 63) >> 1;
                const bool even = (col & 1) == 0;
                #pragma unroll
                for (int j = 0; j < 4; ++j) {
                    const int row = row0 + j;
                    const float v = acc[m][n][j] + bz;
                    const float pv = __shfl_xor(v, 1);
                    const float2 cs = tbl[row * HALF + p];
                    const float outv = even ? v * cs.x - pv * cs.y
                                            : v * cs.x + pv * cs.y;
                    O[(size_t)row * EMB + col] = f2bf(outv);
                }
            }
        }
    }
}

// ---------------------------------------------------------------------------
// Output projection GEMM, SPLIT-K=2, bf16 partials.
// ---------------------------------------------------------------------------
#define GBM 128
#define GBN 128
#define GBK 64

__global__ __launch_bounds__(256) void gemm_out_sk(
    const ushort* __restrict__ A,
    const ushort* __restrict__ B,
    ushort* __restrict__ P)              // [2][2048][2048] bf16 partials
{
    __shared__ ushort As[GBM * GBK];
    __shared__ ushort Bs[GBN * GBK];
    const int tid  = threadIdx.x;
    const int lane = tid & 63;
    const int wid  = tid >> 6;
    const int bm = blockIdx.y * GBM;
    const int bn = blockIdx.x * GBN;
    const int z  = blockIdx.z;
    const int wr = (wid >> 1) * 64;
    const int wc = (wid & 1) * 64;

    floatx4 acc[4][4] = {};

    const int lrow  = lane >> 3;
    const int lcolb = (lane & 7) * 8;

    for (int k0 = z * 1024; k0 < (z + 1) * 1024; k0 += GBK) {
        #pragma unroll
        for (int c = 0; c < 4; ++c) {
            const int chunk = wid * 4 + c;
            const int row = chunk * 8 + lrow;
            gload_lds16(&A[(size_t)(bm + row) * EMB + k0 + lcolb], &As[chunk * 512]);
            gload_lds16(&B[(size_t)(bn + row) * EMB + k0 + lcolb], &Bs[chunk * 512]);
        }
        __syncthreads();
        #pragma unroll
        for (int kk = 0; kk < 2; ++kk) {
            short8v a[4], b[4];
            #pragma unroll
            for (int m = 0; m < 4; ++m)
                a[m] = *reinterpret_cast<const short8v*>(
                    &As[(wr + m * 16 + (lane & 15)) * GBK + kk * 32 + (lane >> 4) * 8]);
            #pragma unroll
            for (int n = 0; n < 4; ++n)
                b[n] = *reinterpret_cast<const short8v*>(
                    &Bs[(wc + n * 16 + (lane & 15)) * GBK + kk * 32 + (lane >> 4) * 8]);
            #pragma unroll
            for (int m = 0; m < 4; ++m)
                #pragma unroll
                for (int n = 0; n < 4; ++n)
                    acc[m][n] = __builtin_amdgcn_mfma_f32_16x16x32_bf16(
                        a[m], b[n], acc[m][n], 0, 0, 0);
        }
        __syncthreads();
    }

    ushort* Pz = P + (size_t)z * 4194304;
    const int cr = (lane >> 4) * 4;
    const int cc = lane & 15;
    #pragma unroll
    for (int m = 0; m < 4; ++m) {
        #pragma unroll
        for (int n = 0; n < 4; ++n) {
            const int col = bn + wc + n * 16 + cc;
            #pragma unroll
            for (int j = 0; j < 4; ++j) {
                const int row = bm + wr + m * 16 + cr + j;
                Pz[(size_t)row * EMB + col] = f2bf(acc[m][n][j]);
            }
        }
    }
}

// out = P0 + P1 + bias  (bf16 partials -> fp32 out, 8 elem/thread)
__global__ __launch_bounds__(256) void reduce_out(
    const ushort* __restrict__ P, const float* __restrict__ bias,
    float* __restrict__ C)
{
    const int i = (blockIdx.x * 256 + threadIdx.x) * 8;
    const uint4 pa = *reinterpret_cast<const uint4*>(&P[i]);
    const uint4 pb = *reinterpret_cast<const uint4*>(&P[4194304 + i]);
    const ushort* ua = reinterpret_cast<const ushort*>(&pa);
    const ushort* ub = reinterpret_cast<const ushort*>(&pb);
    const int cb = i & 2047;
    float o[8];
    #pragma unroll
    for (int j = 0; j < 8; ++j) {
        union { unsigned u; float f; } fa, fb;
        fa.u = (unsigned)ua[j] << 16;
        fb.u = (unsigned)ub[j] << 16;
        o[j] = fa.f + fb.f + bias[cb + j];
    }
    *reinterpret_cast<float4*>(&C[i])     = make_float4(o[0], o[1], o[2], o[3]);
    *reinterpret_cast<float4*>(&C[i + 4]) = make_float4(o[4], o[5], o[6], o[7]);
}

// ---------------------------------------------------------------------------
// Flash attention, 32x32 MFMA, P fully IN-REGISTER (T12 structure).
// 4 warps x 32 q-rows = 128-row q-blocks; grid (NH, 16) = 512 blocks (2/CU).
// Swapped QK^T: S^T tile = mfma32(K_frag, Q_frag) -> lane owns q = lane&31;
// lane half hh=lane>>5 holds s = (reg&3)+8*(reg>>2)+4*hh (+32 per s-tile);
// lane^32 holds the complementary 16 -> one shfl_xor(32) completes row
// max/sum. P packed via cvt_pk; 16 shfl_xor(32) + cndmask route the packed
// words into exact PV A-fragments (s-order verified reg-by-reg). V consumed
// from Vt LDS as B-operand (col=d=lane&31). O acc: d=lane&31, q per reg.
// LDS 32 KB (no P buffer). Defer-max, exp2 (log2e in Q table), LPT order.
// ---------------------------------------------------------------------------
__global__ __launch_bounds__(256) void flash_attn_mfma32(
    const ushort* __restrict__ Qb,   // [T][EMB] bf16 (rotary+scaled, log2e)
    const ushort* __restrict__ Kb,   // [T][EMB] bf16 (rotary)
    const ushort* __restrict__ Vt,   // [EMB][T] bf16 (per-head [d][t])
    ushort* __restrict__ Ob)         // [T][EMB] bf16
{
    __shared__ ushort Ks[2][64 * 64];    // 2 x 8 KB
    __shared__ ushort Vs[2][64 * 64];    // 2 x 8 KB

    const int h   = blockIdx.x;
    const int qb  = (T_LEN / 128 - 1) - blockIdx.y;  // 0..15, LPT order
    const int tid = threadIdx.x;
    const int lane = tid & 63;
    const int wid  = tid >> 6;           // 4 warps
    const int qrow_w = qb * 128 + wid * 32;
    const int lq = lane & 31;            // this lane's q row
    const int hh = lane >> 5;            // k-half

    // Q as B-operand: chunk c covers d = c*16 + hh*8 .. +7
    short8v qf[4];
    {
        const ushort* qp = &Qb[(size_t)(qrow_w + lq) * EMB + h * HD + hh * 8];
        qf[0] = *reinterpret_cast<const short8v*>(qp);
        qf[1] = *reinterpret_cast<const short8v*>(qp + 16);
        qf[2] = *reinterpret_cast<const short8v*>(qp + 32);
        qf[3] = *reinterpret_cast<const short8v*>(qp + 48);
    }

    floatx16 oacc[2] = {};    // d-tiles; lane d = dt*32+lq, q per reg
    float m = -1e30f, l = 0.f;

    const int srow = lane >> 3;
    const int schk = lane & 7;
    const int nkb = 2 * qb + 2;

    // prologue: stage tile 0 (4 warps x {2 K slots + 2 V slots})
    #pragma unroll
    for (int i = 0; i < 2; ++i) {
        const int slot = wid * 2 + i;
        const int row  = slot * 8 + srow;
        const int cswz = (schk ^ (row & 7)) * 8;
        gload_lds16(&Kb[(size_t)row * EMB + h * HD + cswz], &Ks[0][slot * 512]);
        gload_lds16(&Vt[(size_t)(h * HD + row) * T_LEN + cswz], &Vs[0][slot * 512]);
    }
    __syncthreads();

    for (int kb = 0; kb < nkb; ++kb) {
        const int cur = kb & 1;
        if (kb + 1 < nkb) {
            const int nk = kb + 1;
            #pragma unroll
            for (int i = 0; i < 2; ++i) {
                const int slot = wid * 2 + i;
                const int row  = slot * 8 + srow;
                const int cswz = (schk ^ (row & 7)) * 8;
                gload_lds16(&Kb[(size_t)(nk * 64 + row) * EMB + h * HD + cswz],
                            &Ks[cur ^ 1][slot * 512]);
                gload_lds16(&Vt[(size_t)(h * HD + row) * T_LEN + nk * 64 + cswz],
                            &Vs[cur ^ 1][slot * 512]);
            }
        }

        if (kb * 64 <= qrow_w + 31) {    // warp-uniform causal skip
            const bool diag = (kb * 64 + 63 > qrow_w);

            // ---- QK^T: 2 s-tiles x 4 d-chunks of 32x32x16
            floatx16 sacc[2] = {};
            __builtin_amdgcn_s_setprio(1);
            #pragma unroll
            for (int st = 0; st < 2; ++st) {
                const int srow_l = st * 32 + lq;        // A row = s
                const char* krow = reinterpret_cast<const char*>(Ks[cur])
                                 + srow_l * 128;
                const int swz = srow_l & 7;
                #pragma unroll
                for (int c = 0; c < 4; ++c) {
                    short8v kf = *reinterpret_cast<const short8v*>(
                        krow + (((2 * c + hh) ^ swz) * 16));
                    sacc[st] = __builtin_amdgcn_mfma_f32_32x32x16_bf16(
                        kf, qf[c], sacc[st], 0, 0, 0);
                }
            }
            __builtin_amdgcn_s_setprio(0);

            // ---- extract + causal mask. s(reg r, tile st) =
            //      kb*64 + st*32 + (r&3) + 8*(r>>2) + 4*hh
            float sv[32];
            const int qg = qrow_w + lq;
            #pragma unroll
            for (int st = 0; st < 2; ++st)
                #pragma unroll
                for (int r = 0; r < 16; ++r) {
                    float v = sacc[st][r];
                    if (diag) {
                        const int sg = kb * 64 + st * 32 + (r & 3) + 8 * (r >> 2) + 4 * hh;
                        if (sg > qg) v = -1e30f;
                    }
                    sv[st * 16 + r] = v;
                }

            // ---- row max: tree over 32 local + 1 cross-half swap
            float mx = sv[0];
            #pragma unroll
            for (int i = 1; i < 32; ++i) mx = fmaxf(mx, sv[i]);
            mx = fmaxf(mx, __shfl_xor(mx, 32));

            float corr = 1.f;
            if (!__all(mx - m <= 11.544f)) {   // 8 nats in log2 units
                const float mnew = fmaxf(m, mx);
                corr = exp2f(m - mnew);
                m = mnew;
                #pragma unroll
                for (int r = 0; r < 16; ++r) {
                    const float cr = __shfl(corr, (r & 3) + 8 * (r >> 2) + 4 * hh);
                    oacc[0][r] *= cr;
                    oacc[1][r] *= cr;
                }
            }

            // ---- P = exp2(sv - m), pack pairs, sum
            float ps = 0.f;
            unsigned w[16];
            #pragma unroll
            for (int i = 0; i < 16; ++i) {
                const float p0 = exp2f(sv[2 * i + 0] - m);
                const float p1 = exp2f(sv[2 * i + 1] - m);
                ps += p0 + p1;
                const __hip_bfloat162 h2 = __float22bfloat162_rn(make_float2(p0, p1));
                w[i] = *reinterpret_cast<const unsigned*>(&h2);
            }
            ps += __shfl_xor(ps, 32);
            l = l * corr + ps;

            // partner words (lane^32 holds the complementary s quads)
            unsigned px[16];
            #pragma unroll
            for (int i = 0; i < 16; ++i)
                px[i] = (unsigned)__shfl_xor((int)w[i], 32);

            // ---- PV: 4 s-chunks x 2 d-tiles of 32x32x16
            __builtin_amdgcn_s_setprio(1);
            #pragma unroll
            for (int c = 0; c < 4; ++c) {
                // A-frag routing (verified): word base = (c>>1)*8 + (c&1)*4
                const int b4 = (c >> 1) * 8 + (c & 1) * 4;
                unsigned aw[4];
                aw[0] = hh ? px[b4 + 2] : w[b4 + 0];
                aw[1] = hh ? px[b4 + 3] : w[b4 + 1];
                aw[2] = hh ? w[b4 + 2] : px[b4 + 0];
                aw[3] = hh ? w[b4 + 3] : px[b4 + 1];
                short8v pa = *reinterpret_cast<const short8v*>(aw);
                #pragma unroll
                for (int dt = 0; dt < 2; ++dt) {
                    const int d = dt * 32 + lq;
                    short8v vb = *reinterpret_cast<const short8v*>(
                        reinterpret_cast<const char*>(Vs[cur]) + d * 128
                        + (((2 * c + hh) ^ (d & 7)) * 16));
                    oacc[dt] = __builtin_amdgcn_mfma_f32_32x32x16_bf16(
                        pa, vb, oacc[dt], 0, 0, 0);
                }
            }
            __builtin_amdgcn_s_setprio(0);
        }

        __syncthreads();   // drains prefetch + all warps done with buf[cur]
    }

    // ---- epilogue: O[q, d] = oacc / l[q]
    #pragma unroll
    for (int r = 0; r < 16; ++r) {
        const int qr = (r & 3) + 8 * (r >> 2) + 4 * hh;
        const float invl = 1.f / __shfl(l, qr);
        const size_t rowoff = (size_t)(qrow_w + qr) * EMB + h * HD;
        Ob[rowoff + lq]      = f2bf(oacc[0][r] * invl);
        Ob[rowoff + 32 + lq] = f2bf(oacc[1][r] * invl);
    }
}

// ---------------------------------------------------------------------------
// Launch. 5 dispatches. Workspace (90 MB):
//   +0  [Wq|Wk|Wv] bf16 (24MB stacked)  +24 bWo
//   +32 [bAq|bAk|bAv] bf16 (24MB; dead after qkv8 -> bf16 partials 16MB)
//   +56 bQ   +64 bK   +72 bVt  +80 bAo   +88 qtab (512KB)  +88.5 ktab (512KB)
// ---------------------------------------------------------------------------
extern "C" void kernel_launch(void* const* d_in, const int* in_sizes, int n_in,
                              void* d_out, int out_size, void* d_ws, size_t ws_size,
                              hipStream_t stream) {
    const float* query = (const float*)d_in[0];
    const float* key   = (const float*)d_in[1];
    const float* value = (const float*)d_in[2];
    const float* Wq = (const float*)d_in[3];
    const float* bq = (const float*)d_in[4];
    const float* Wk = (const float*)d_in[5];
    const float* bk = (const float*)d_in[6];
    const float* Wv = (const float*)d_in[7];
    const float* bv = (const float*)d_in[8];
    const float* Wo = (const float*)d_in[9];
    const float* bo = (const float*)d_in[10];
    const float* sinp   = (const float*)d_in[11];
    const float* cosp   = (const float*)d_in[12];
    const float* xscale = (const float*)d_in[13];
    float* out = (float*)d_out;

    const size_t MB = 1024 * 1024;
    char* ws = (char*)d_ws;
    ushort* bWqkv = (ushort*)(ws + 0 * MB);
    ushort* bWo   = (ushort*)(ws + 24 * MB);
    ushort* bAqkv = (ushort*)(ws + 32 * MB);
    ushort* bQ  = (ushort*)(ws + 56 * MB);
    ushort* bK  = (ushort*)(ws + 64 * MB);
    ushort* bVt = (ushort*)(ws + 72 * MB);
    ushort* bAo = (ushort*)(ws + 80 * MB);
    float2* qtab = (float2*)(ws + 88 * MB);
    float2* ktab = (float2*)(ws + 88 * MB + 512 * 1024);
    ushort* Pout = (ushort*)(ws + 32 * MB);  // 16MB bf16 partials (overlay)

    conv_all<<<14336 + 256, 256, 0, stream>>>(
        Wq, Wk, Wv, Wo, query, key, value, bWqkv,
        sinp, cosp, xscale, qtab, ktab);

    dim3 gQKV(24, 8);                          // 192 blocks, 512 thr
    gemm_qkv8<<<gQKV, 512, 0, stream>>>(bAqkv, bWqkv, bq, bk, bv,
                                        bQ, bK, bVt, qtab, ktab);

    dim3 gFlash(NH, T_LEN / 128);              // 512 blocks, 128 q-rows each
    flash_attn_mfma32<<<gFlash, 256, 0, stream>>>(bQ, bK, bVt, bAo);

    dim3 gOut(EMB / GBN, T_LEN / GBM, 2);      // split-K=2: 512 blocks
    gemm_out_sk<<<gOut, 256, 0, stream>>>(bAo, bWo, Pout);
    reduce_out<<<T_LEN * EMB / (256 * 8), 256, 0, stream>>>(Pout, bo, out);
}

// Round 14
// 171.427 us; speedup vs baseline: 1.1877x; 1.1877x over previous
//
#include <hip/hip_runtime.h>
#include <hip/hip_bf16.h>
#include <math.h>

// Problem constants (fixed by harness)
#define T_LEN 2048
#define EMB   2048
#define NH    32
#define HD    64
#define HALF  32

typedef __attribute__((ext_vector_type(8))) short short8v;   // 8 bf16 (4 VGPR)
typedef __attribute__((ext_vector_type(4))) float floatx4;   // MFMA C/D

// async global->LDS, 16B per lane. LDS dest is wave-uniform base + lane*16.
__device__ inline void gload_lds16(const void* g, void* l) {
    __builtin_amdgcn_global_load_lds(
        (const __attribute__((address_space(1))) unsigned int*)g,
        (__attribute__((address_space(3))) unsigned int*)l,
        16, 0, 0);
}

__device__ inline ushort f2bf(float x) {
    union { float f; unsigned u; } c; c.f = x;
    const unsigned r = c.u + 0x7FFFu + ((c.u >> 16) & 1u);  // RNE
    return (ushort)(r >> 16);
}

// raw barrier with compiler memory fences (NO vmcnt drain, unlike __syncthreads)
#define BARRIER() do { asm volatile("" ::: "memory"); \
    __builtin_amdgcn_s_barrier(); asm volatile("" ::: "memory"); } while (0)
#define VMW8() asm volatile("s_waitcnt vmcnt(8)" ::: "memory")
#define VMW0() asm volatile("s_waitcnt vmcnt(0)" ::: "memory")

// ---------------------------------------------------------------------------
// Fused: fp32->bf16 conversion of all 7 tensors (blocks 0..14335) + rotary
// coefficient tables (blocks 14336..14591). Q table folds xscale *
// scale_attention * HD^-0.5 * log2(e); K table = 1/xscale.
// ---------------------------------------------------------------------------
__global__ __launch_bounds__(256) void conv_all(
    const float* __restrict__ s0, const float* __restrict__ s1,
    const float* __restrict__ s2, const float* __restrict__ s3,
    const float* __restrict__ s4, const float* __restrict__ s5,
    const float* __restrict__ s6, ushort* __restrict__ dst,
    const float* __restrict__ sinp, const float* __restrict__ cosp,
    const float* __restrict__ xscale,
    float2* __restrict__ qt, float2* __restrict__ kt)
{
    if (blockIdx.x >= 14336) {
        const int idx = (blockIdx.x - 14336) * 256 + threadIdx.x;  // 65536
        const int t = idx >> 5;
        const float s = sinp[idx], c = cosp[idx], xs = xscale[idx];
        float sa = 1.f;
        if (t >= 2) {
            const float lv = __logf((float)t) * 0.14426950408889634f; // /ln(1024)
            sa = lv > 1.f ? lv : 1.f;
        }
        const float qs = xs * sa * 0.125f * 1.4426950408889634f;  // * log2(e)
        qt[idx] = make_float2(c * qs, s * qs);
        const float ks = 1.f / xs;
        kt[idx] = make_float2(c * ks, s * ks);
        return;
    }
    const int idx = blockIdx.x * 256 + threadIdx.x;   // 7 * 2^19 threads
    const int t = idx >> 19;
    const int r = (idx & 524287) * 8;
    const float* in = t == 0 ? s0 : t == 1 ? s1 : t == 2 ? s2 : t == 3 ? s3
                    : t == 4 ? s4 : t == 5 ? s5 : s6;
    const float4 v0 = *reinterpret_cast<const float4*>(&in[r]);
    const float4 v1 = *reinterpret_cast<const float4*>(&in[r + 4]);
    ushort o[8];
    o[0] = f2bf(v0.x); o[1] = f2bf(v0.y); o[2] = f2bf(v0.z); o[3] = f2bf(v0.w);
    o[4] = f2bf(v1.x); o[5] = f2bf(v1.y); o[6] = f2bf(v1.z); o[7] = f2bf(v1.w);
    *reinterpret_cast<uint4*>(&dst[(size_t)t * 4194304 + r]) =
        *reinterpret_cast<const uint4*>(o);
}

// ---------------------------------------------------------------------------
// QKV projection, 256x256-tile 8-phase GEMM, 3-slot-A pipeline (measured
// plateau ~70.6 µs; kept). ALL slot indices compile-time (round-7 lesson).
// ---------------------------------------------------------------------------
#define QBM 256
#define QBN 256

#define STAGE_A3(tau, h, slot) do {                                            \
    const int _tc = (tau) * 64;                                                \
    _Pragma("unroll") for (int _i = 0; _i < 2; ++_i) {                         \
        gload_lds16(&Ap[(size_t)(bm + (h) * 128 + wid * 16 + _i * 8 + rl) * 2048 + _tc + csw], \
                    &lds[(slot) * 16384 + (h) * 8192 + (wid * 16 + _i * 8) * 64]); \
    } } while (0)

#define STAGE_B2(tau, h, slot) do {                                            \
    const int _tc = (tau) * 64;                                                \
    _Pragma("unroll") for (int _i = 0; _i < 2; ++_i) {                         \
        gload_lds16(&Bp[(size_t)(bn + (h) * 128 + wid * 16 + _i * 8 + rl) * 2048 + _tc + csw], \
                    &lds[49152 + (slot) * 16384 + (h) * 8192 + (wid * 16 + _i * 8) * 64]); \
    } } while (0)

#define PH(sa_, sb_, mp, VMWSTMT, ...) do {                                    \
    if ((mp) == 0) {                                                           \
        _Pragma("unroll") for (int n = 0; n < 4; ++n) {                        \
            bf[n][0] = ldB(sb_, n, 0);                                         \
            bf[n][1] = ldB(sb_, n, 1);                                         \
        }                                                                      \
    }                                                                          \
    af[0][0] = ldA(sa_, (mp) * 2, 0);     af[0][1] = ldA(sa_, (mp) * 2, 1);    \
    af[1][0] = ldA(sa_, (mp) * 2 + 1, 0); af[1][1] = ldA(sa_, (mp) * 2 + 1, 1);\
    __VA_ARGS__;                                                               \
    BARRIER();                                                                 \
    __builtin_amdgcn_s_setprio(1);                                             \
    _Pragma("unroll") for (int mm = 0; mm < 2; ++mm)                           \
    _Pragma("unroll") for (int n = 0; n < 4; ++n)                              \
    _Pragma("unroll") for (int kk = 0; kk < 2; ++kk)                           \
        acc[(mp) * 2 + mm][n] = __builtin_amdgcn_mfma_f32_16x16x32_bf16(       \
            af[mm][kk], bf[n][kk], acc[(mp) * 2 + mm][n], 0, 0, 0);            \
    __builtin_amdgcn_s_setprio(0);                                             \
    VMWSTMT;                                                                   \
    BARRIER();                                                                 \
} while (0)

#define TILE6(sa, sb, sa2, tau2, LASTVMW) do {                                 \
    PH(sa, sb, 0, (void)0, STAGE_A3(tau2, 0, sa2));                            \
    PH(sa, sb, 1, (void)0, STAGE_A3(tau2, 1, sa2));                            \
    PH(sa, sb, 2, (void)0, STAGE_B2(tau2, 0, sb));                             \
    PH(sa, sb, 3, LASTVMW, STAGE_B2(tau2, 1, sb));                             \
} while (0)

__global__ __launch_bounds__(512, 2) void gemm_qkv8(
    const ushort* __restrict__ Astack,   // [Aq|Ak|Av] bf16, each [2048][2048]
    const ushort* __restrict__ Wstack,   // [Wq|Wk|Wv] bf16, each [2048][2048]
    const float* __restrict__ bq, const float* __restrict__ bk,
    const float* __restrict__ bv,
    ushort* __restrict__ outQ, ushort* __restrict__ outK,
    ushort* __restrict__ outVt,
    const float2* __restrict__ qtab, const float2* __restrict__ ktab)
{
    __shared__ ushort lds[81920];   // 160 KiB: A 3x32KB | B 2x32KB
    const int tid  = threadIdx.x;
    const int lane = tid & 63;
    const int wid  = tid >> 6;      // 0..7

    const int b   = blockIdx.x + blockIdx.y * 24;  // 0..191
    const int xcd = b & 7;
    const int idx = b >> 3;                        // 0..23
    const int bx  = xcd * 3 + (idx >> 3);          // 0..23 col-panel
    const int by  = idx & 7;                       // 0..7  row-panel
    const int which = bx >> 3;                     // 0=Q 1=K 2=V
    const int bn  = (bx & 7) * QBN;
    const int bm  = by * QBM;
    const ushort* Ap = Astack + (size_t)which * 4194304;
    const ushort* Bp = Wstack + (size_t)which * 4194304;

    const int rl  = lane >> 3;
    const int csw = (((lane & 7) ^ ((lane >> 3) & 7)) * 8);
    const int lm  = lane & 15;
    const int lg  = lane >> 4;
    const char* ldsb = reinterpret_cast<const char*>(lds);

    auto ldA = [&](int slot, int m, int kk) -> short8v {
        const int row = m * 16 + lm;
        const int off = (slot * 16384 + (wid >> 2) * 8192) * 2 + row * 128
                      + (((kk * 4 + lg) ^ (row & 7)) * 16);
        return *reinterpret_cast<const short8v*>(ldsb + off);
    };
    auto ldB = [&](int slot, int n, int kk) -> short8v {
        const int row = (wid & 1) * 64 + n * 16 + lm;
        const int off = (49152 + slot * 16384 + ((wid & 3) >> 1) * 8192) * 2
                      + row * 128 + (((kk * 4 + lg) ^ (row & 7)) * 16);
        return *reinterpret_cast<const short8v*>(ldsb + off);
    };

    floatx4 acc[8][4] = {};
    short8v bf[4][2];
    short8v af[2][2];

    STAGE_A3(0, 0, 0); STAGE_A3(0, 1, 0);
    STAGE_B2(0, 0, 0); STAGE_B2(0, 1, 0);
    STAGE_A3(1, 0, 1); STAGE_A3(1, 1, 1);
    STAGE_B2(1, 0, 1); STAGE_B2(1, 1, 1);
    VMW8();
    BARRIER();

    for (int i = 0; i < 5; ++i) {
        const int t = 6 * i;
        TILE6(0, 0, 2, t + 2, VMW8());
        TILE6(1, 1, 0, t + 3, VMW8());
        TILE6(2, 0, 1, t + 4, VMW8());
        TILE6(0, 1, 2, t + 5, VMW8());
        TILE6(1, 0, 0, t + 6, VMW8());
        TILE6(2, 1, 1, t + 7, VMW8());
    }
    PH(0, 0, 0, (void)0, (void)0);
    PH(0, 0, 1, (void)0, (void)0);
    PH(0, 0, 2, (void)0, (void)0);
    PH(0, 0, 3, VMW0(),  (void)0);
    PH(1, 1, 0, (void)0, (void)0);
    PH(1, 1, 1, (void)0, (void)0);
    PH(1, 1, 2, (void)0, (void)0);
    PH(1, 1, 3, (void)0, (void)0);

    const float* bias = which == 0 ? bq : which == 1 ? bk : bv;
    const float2* tbl = which == 0 ? qtab : ktab;
    #pragma unroll
    for (int m = 0; m < 8; ++m) {
        #pragma unroll
        for (int n = 0; n < 4; ++n) {
            const int col = bn + (wid & 3) * 64 + n * 16 + lm;
            const float bz = bias[col];
            const int row0 = bm + (wid >> 2) * 128 + m * 16 + lg * 4;
            if (which == 2) {
                ushort o4[4];
                #pragma unroll
                for (int j = 0; j < 4; ++j)
                    o4[j] = f2bf(acc[m][n][j] + bz);
                *reinterpret_cast<uint2*>(&outVt[(size_t)col * T_LEN + row0]) =
                    *reinterpret_cast<const uint2*>(o4);
            } else {
                ushort* O = which == 0 ? outQ : outK;
                const int p = (col & 63) >> 1;
                const bool even = (col & 1) == 0;
                #pragma unroll
                for (int j = 0; j < 4; ++j) {
                    const int row = row0 + j;
                    const float v = acc[m][n][j] + bz;
                    const float pv = __shfl_xor(v, 1);
                    const float2 cs = tbl[row * HALF + p];
                    const float outv = even ? v * cs.x - pv * cs.y
                                            : v * cs.x + pv * cs.y;
                    O[(size_t)row * EMB + col] = f2bf(outv);
                }
            }
        }
    }
}

// ---------------------------------------------------------------------------
// Output projection GEMM, SPLIT-K=2, bf16 partials.
// ---------------------------------------------------------------------------
#define GBM 128
#define GBN 128
#define GBK 64

__global__ __launch_bounds__(256) void gemm_out_sk(
    const ushort* __restrict__ A,
    const ushort* __restrict__ B,
    ushort* __restrict__ P)              // [2][2048][2048] bf16 partials
{
    __shared__ ushort As[GBM * GBK];
    __shared__ ushort Bs[GBN * GBK];
    const int tid  = threadIdx.x;
    const int lane = tid & 63;
    const int wid  = tid >> 6;
    const int bm = blockIdx.y * GBM;
    const int bn = blockIdx.x * GBN;
    const int z  = blockIdx.z;
    const int wr = (wid >> 1) * 64;
    const int wc = (wid & 1) * 64;

    floatx4 acc[4][4] = {};

    const int lrow  = lane >> 3;
    const int lcolb = (lane & 7) * 8;

    for (int k0 = z * 1024; k0 < (z + 1) * 1024; k0 += GBK) {
        #pragma unroll
        for (int c = 0; c < 4; ++c) {
            const int chunk = wid * 4 + c;
            const int row = chunk * 8 + lrow;
            gload_lds16(&A[(size_t)(bm + row) * EMB + k0 + lcolb], &As[chunk * 512]);
            gload_lds16(&B[(size_t)(bn + row) * EMB + k0 + lcolb], &Bs[chunk * 512]);
        }
        __syncthreads();
        #pragma unroll
        for (int kk = 0; kk < 2; ++kk) {
            short8v a[4], b[4];
            #pragma unroll
            for (int m = 0; m < 4; ++m)
                a[m] = *reinterpret_cast<const short8v*>(
                    &As[(wr + m * 16 + (lane & 15)) * GBK + kk * 32 + (lane >> 4) * 8]);
            #pragma unroll
            for (int n = 0; n < 4; ++n)
                b[n] = *reinterpret_cast<const short8v*>(
                    &Bs[(wc + n * 16 + (lane & 15)) * GBK + kk * 32 + (lane >> 4) * 8]);
            #pragma unroll
            for (int m = 0; m < 4; ++m)
                #pragma unroll
                for (int n = 0; n < 4; ++n)
                    acc[m][n] = __builtin_amdgcn_mfma_f32_16x16x32_bf16(
                        a[m], b[n], acc[m][n], 0, 0, 0);
        }
        __syncthreads();
    }

    ushort* Pz = P + (size_t)z * 4194304;
    const int cr = (lane >> 4) * 4;
    const int cc = lane & 15;
    #pragma unroll
    for (int m = 0; m < 4; ++m) {
        #pragma unroll
        for (int n = 0; n < 4; ++n) {
            const int col = bn + wc + n * 16 + cc;
            #pragma unroll
            for (int j = 0; j < 4; ++j) {
                const int row = bm + wr + m * 16 + cr + j;
                Pz[(size_t)row * EMB + col] = f2bf(acc[m][n][j]);
            }
        }
    }
}

// out = P0 + P1 + bias  (bf16 partials -> fp32 out, 8 elem/thread)
__global__ __launch_bounds__(256) void reduce_out(
    const ushort* __restrict__ P, const float* __restrict__ bias,
    float* __restrict__ C)
{
    const int i = (blockIdx.x * 256 + threadIdx.x) * 8;
    const uint4 pa = *reinterpret_cast<const uint4*>(&P[i]);
    const uint4 pb = *reinterpret_cast<const uint4*>(&P[4194304 + i]);
    const ushort* ua = reinterpret_cast<const ushort*>(&pa);
    const ushort* ub = reinterpret_cast<const ushort*>(&pb);
    const int cb = i & 2047;
    float o[8];
    #pragma unroll
    for (int j = 0; j < 8; ++j) {
        union { unsigned u; float f; } fa, fb;
        fa.u = (unsigned)ua[j] << 16;
        fb.u = (unsigned)ub[j] << 16;
        o[j] = fa.f + fb.f + bias[cb + j];
    }
    *reinterpret_cast<float4*>(&C[i])     = make_float4(o[0], o[1], o[2], o[3]);
    *reinterpret_cast<float4*>(&C[i + 4]) = make_float4(o[4], o[5], o[6], o[7]);
}

// ---------------------------------------------------------------------------
// MFMA flash attention — ROUND-12 EXACT kernel (measured ~36 µs; round-13's
// 32x32 in-register variant regressed to 85 µs: serial 31-op max chain +
// 2 blocks/CU occupancy — reverted). 64 q-rows/block, 40 KB LDS, 1024
// blocks; T5 setprio around MFMA clusters; tree max/sum reductions;
// 2-phase pipelined staging; defer-max; exp2 (log2e in Q table); cvt_pk
// P-packing; LPT block order.
// ---------------------------------------------------------------------------
__global__ __launch_bounds__(256) void flash_attn_mfma(
    const ushort* __restrict__ Qb,   // [T][EMB] bf16 (rotary+scaled, log2e)
    const ushort* __restrict__ Kb,   // [T][EMB] bf16 (rotary)
    const ushort* __restrict__ Vt,   // [EMB][T] bf16 (per-head [d][t])
    ushort* __restrict__ Ob)         // [T][EMB] bf16
{
    __shared__ ushort Ks[2][64 * 64];
    __shared__ ushort Vs[2][64 * 64];
    __shared__ ushort Ps[4][16 * 64];

    const int h   = blockIdx.x;
    const int qb  = (T_LEN / 64 - 1) - blockIdx.y;   // LPT: heavy blocks first
    const int tid = threadIdx.x;
    const int lane = tid & 63;
    const int wid  = tid >> 6;
    const int qrow_w = qb * 64 + wid * 16;
    const int lm = lane & 15;
    const int lg = lane >> 4;

    short8v qf[2];
    {
        const ushort* qp = &Qb[(size_t)(qrow_w + lm) * EMB + h * HD + lg * 8];
        qf[0] = *reinterpret_cast<const short8v*>(qp);
        qf[1] = *reinterpret_cast<const short8v*>(qp + 32);
    }

    floatx4 oacc[4] = {};
    float m = -1e30f, l = 0.f;

    const int srow = lane >> 3;
    const int schk = lane & 7;

    {
        #pragma unroll
        for (int i = 0; i < 2; ++i) {
            const int slot = wid * 2 + i;
            const int row  = slot * 8 + srow;
            const int cswz = (schk ^ (row & 7)) * 8;
            gload_lds16(&Kb[(size_t)row * EMB + h * HD + cswz], &Ks[0][slot * 512]);
            gload_lds16(&Vt[(size_t)(h * HD + row) * T_LEN + cswz], &Vs[0][slot * 512]);
        }
    }
    __syncthreads();

    for (int kb = 0; kb <= qb; ++kb) {
        const int cur = kb & 1;
        if (kb < qb) {
            const int nkb = kb + 1;
            #pragma unroll
            for (int i = 0; i < 2; ++i) {
                const int slot = wid * 2 + i;
                const int row  = slot * 8 + srow;
                const int cswz = (schk ^ (row & 7)) * 8;
                gload_lds16(&Kb[(size_t)(nkb * 64 + row) * EMB + h * HD + cswz],
                            &Ks[cur ^ 1][slot * 512]);
                gload_lds16(&Vt[(size_t)(h * HD + row) * T_LEN + nkb * 64 + cswz],
                            &Vs[cur ^ 1][slot * 512]);
            }
        }

        float sv[16];
        __builtin_amdgcn_s_setprio(1);
        #pragma unroll
        for (int t = 0; t < 4; ++t) {
            floatx4 sacc = {};
            const int srow_l = t * 16 + lm;
            const char* krow = reinterpret_cast<const char*>(Ks[cur]) + srow_l * 128;
            const int swz = (srow_l & 7) << 4;
            #pragma unroll
            for (int kk = 0; kk < 2; ++kk) {
                const int cb = (kk * 64 + lg * 16) ^ swz;
                short8v kf = *reinterpret_cast<const short8v*>(krow + cb);
                sacc = __builtin_amdgcn_mfma_f32_16x16x32_bf16(kf, qf[kk], sacc, 0, 0, 0);
            }
            sv[t * 4 + 0] = sacc[0]; sv[t * 4 + 1] = sacc[1];
            sv[t * 4 + 2] = sacc[2]; sv[t * 4 + 3] = sacc[3];
        }
        __builtin_amdgcn_s_setprio(0);

        const int qg = qrow_w + lm;
        if (kb == qb) {
            #pragma unroll
            for (int t = 0; t < 4; ++t)
                #pragma unroll
                for (int r = 0; r < 4; ++r) {
                    const int sg = kb * 64 + t * 16 + lg * 4 + r;
                    if (sg > qg) sv[t * 4 + r] = -1e30f;
                }
        }

        // tree max (depth 4; fmaxf triples fusable to v_max3)
        const float mx0 = fmaxf(fmaxf(fmaxf(sv[0], sv[1]), fmaxf(sv[2], sv[3])),
                                fmaxf(fmaxf(sv[4], sv[5]), fmaxf(sv[6], sv[7])));
        const float mx1 = fmaxf(fmaxf(fmaxf(sv[8], sv[9]), fmaxf(sv[10], sv[11])),
                                fmaxf(fmaxf(sv[12], sv[13]), fmaxf(sv[14], sv[15])));
        float mx = fmaxf(mx0, mx1);
        mx = fmaxf(mx, __shfl_xor(mx, 16));
        mx = fmaxf(mx, __shfl_xor(mx, 32));
        float corr = 1.f;
        if (!__all(mx - m <= 11.544f)) {      // 8 nats in log2 units
            const float mnew = fmaxf(m, mx);
            corr = exp2f(m - mnew);
            m = mnew;
            float corr4[4];
            #pragma unroll
            for (int r = 0; r < 4; ++r)
                corr4[r] = __shfl(corr, lg * 4 + r);
            #pragma unroll
            for (int td = 0; td < 4; ++td)
                #pragma unroll
                for (int r = 0; r < 4; ++r)
                    oacc[td][r] *= corr4[r];
        }
        float psum[8];
        unsigned pw[8];
        #pragma unroll
        for (int i = 0; i < 8; ++i) {
            const float p0 = exp2f(sv[2 * i + 0] - m);
            const float p1 = exp2f(sv[2 * i + 1] - m);
            psum[i] = p0 + p1;
            const __hip_bfloat162 h2 = __float22bfloat162_rn(make_float2(p0, p1));
            pw[i] = *reinterpret_cast<const unsigned*>(&h2);
        }
        float ps = ((psum[0] + psum[1]) + (psum[2] + psum[3]))
                 + ((psum[4] + psum[5]) + (psum[6] + psum[7]));
        ps += __shfl_xor(ps, 16);
        ps += __shfl_xor(ps, 32);
        l = l * corr + ps;

        {
            char* pbase = reinterpret_cast<char*>(&Ps[wid][0]) + lm * 128;
            const int swz = (lm & 7) << 4;
            #pragma unroll
            for (int t = 0; t < 4; ++t) {
                uint2 w;
                w.x = pw[2 * t + 0];
                w.y = pw[2 * t + 1];
                const int cb = (t * 32 + lg * 8) ^ swz;
                *reinterpret_cast<uint2*>(pbase + cb) = w;
            }
        }

        const char* pwave = reinterpret_cast<const char*>(&Ps[wid][0]);
        __builtin_amdgcn_s_setprio(1);
        #pragma unroll
        for (int kk = 0; kk < 2; ++kk) {
            const int acb = (kk * 64 + lg * 16) ^ ((lm & 7) << 4);
            short8v pa = *reinterpret_cast<const short8v*>(pwave + lm * 128 + acb);
            #pragma unroll
            for (int td = 0; td < 4; ++td) {
                const int d = td * 16 + lm;
                const int bcb = (kk * 64 + lg * 16) ^ ((d & 7) << 4);
                short8v vb = *reinterpret_cast<const short8v*>(
                    reinterpret_cast<const char*>(Vs[cur]) + d * 128 + bcb);
                oacc[td] = __builtin_amdgcn_mfma_f32_16x16x32_bf16(pa, vb, oacc[td], 0, 0, 0);
            }
        }
        __builtin_amdgcn_s_setprio(0);

        __syncthreads();
    }

    float invl[4];
    #pragma unroll
    for (int r = 0; r < 4; ++r)
        invl[r] = 1.f / __shfl(l, lg * 4 + r);
    #pragma unroll
    for (int td = 0; td < 4; ++td) {
        #pragma unroll
        for (int r = 0; r < 4; ++r) {
            const int trow = qrow_w + lg * 4 + r;
            const int col  = h * HD + td * 16 + lm;
            Ob[(size_t)trow * EMB + col] = f2bf(oacc[td][r] * invl[r]);
        }
    }
}

// ---------------------------------------------------------------------------
// Launch. 5 dispatches. Workspace (90 MB):
//   +0  [Wq|Wk|Wv] bf16 (24MB stacked)  +24 bWo
//   +32 [bAq|bAk|bAv] bf16 (24MB; dead after qkv8 -> bf16 partials 16MB)
//   +56 bQ   +64 bK   +72 bVt  +80 bAo   +88 qtab (512KB)  +88.5 ktab (512KB)
// ---------------------------------------------------------------------------
extern "C" void kernel_launch(void* const* d_in, const int* in_sizes, int n_in,
                              void* d_out, int out_size, void* d_ws, size_t ws_size,
                              hipStream_t stream) {
    const float* query = (const float*)d_in[0];
    const float* key   = (const float*)d_in[1];
    const float* value = (const float*)d_in[2];
    const float* Wq = (const float*)d_in[3];
    const float* bq = (const float*)d_in[4];
    const float* Wk = (const float*)d_in[5];
    const float* bk = (const float*)d_in[6];
    const float* Wv = (const float*)d_in[7];
    const float* bv = (const float*)d_in[8];
    const float* Wo = (const float*)d_in[9];
    const float* bo = (const float*)d_in[10];
    const float* sinp   = (const float*)d_in[11];
    const float* cosp   = (const float*)d_in[12];
    const float* xscale = (const float*)d_in[13];
    float* out = (float*)d_out;

    const size_t MB = 1024 * 1024;
    char* ws = (char*)d_ws;
    ushort* bWqkv = (ushort*)(ws + 0 * MB);
    ushort* bWo   = (ushort*)(ws + 24 * MB);
    ushort* bAqkv = (ushort*)(ws + 32 * MB);
    ushort* bQ  = (ushort*)(ws + 56 * MB);
    ushort* bK  = (ushort*)(ws + 64 * MB);
    ushort* bVt = (ushort*)(ws + 72 * MB);
    ushort* bAo = (ushort*)(ws + 80 * MB);
    float2* qtab = (float2*)(ws + 88 * MB);
    float2* ktab = (float2*)(ws + 88 * MB + 512 * 1024);
    ushort* Pout = (ushort*)(ws + 32 * MB);  // 16MB bf16 partials (overlay)

    conv_all<<<14336 + 256, 256, 0, stream>>>(
        Wq, Wk, Wv, Wo, query, key, value, bWqkv,
        sinp, cosp, xscale, qtab, ktab);

    dim3 gQKV(24, 8);                          // 192 blocks, 512 thr
    gemm_qkv8<<<gQKV, 512, 0, stream>>>(bAqkv, bWqkv, bq, bk, bv,
                                        bQ, bK, bVt, qtab, ktab);

    dim3 gFlash(NH, T_LEN / 64);               // 1024 blocks, 64 q-rows each
    flash_attn_mfma<<<gFlash, 256, 0, stream>>>(bQ, bK, bVt, bAo);

    dim3 gOut(EMB / GBN, T_LEN / GBM, 2);      // split-K=2: 512 blocks
    gemm_out_sk<<<gOut, 256, 0, stream>>>(bAo, bWo, Pout);
    reduce_out<<<T_LEN * EMB / (256 * 8), 256, 0, stream>>>(Pout, bo, out);
}

// Round 15
// 168.722 us; speedup vs baseline: 1.2067x; 1.0160x over previous
//
#include <hip/hip_runtime.h>
#include <hip/hip_bf16.h>
#include <math.h>

// Problem constants (fixed by harness)
#define T_LEN 2048
#define EMB   2048
#define NH    32
#define HD    64
#define HALF  32

typedef __attribute__((ext_vector_type(8))) short short8v;   // 8 bf16 (4 VGPR)
typedef __attribute__((ext_vector_type(4))) float floatx4;   // MFMA C/D

// async global->LDS, 16B per lane. LDS dest is wave-uniform base + lane*16.
__device__ inline void gload_lds16(const void* g, void* l) {
    __builtin_amdgcn_global_load_lds(
        (const __attribute__((address_space(1))) unsigned int*)g,
        (__attribute__((address_space(3))) unsigned int*)l,
        16, 0, 0);
}

__device__ inline ushort f2bf(float x) {
    union { float f; unsigned u; } c; c.f = x;
    const unsigned r = c.u + 0x7FFFu + ((c.u >> 16) & 1u);  // RNE
    return (ushort)(r >> 16);
}

// raw barrier with compiler memory fences (NO vmcnt drain, unlike __syncthreads)
#define BARRIER() do { asm volatile("" ::: "memory"); \
    __builtin_amdgcn_s_barrier(); asm volatile("" ::: "memory"); } while (0)
#define VMW8() asm volatile("s_waitcnt vmcnt(8)" ::: "memory")
#define VMW0() asm volatile("s_waitcnt vmcnt(0)" ::: "memory")

// ---------------------------------------------------------------------------
// Fused: fp32->bf16 conversion of all 7 tensors (blocks 0..14335) + rotary
// coefficient tables (blocks 14336..14591). Q table folds xscale *
// scale_attention * HD^-0.5 * log2(e); K table = 1/xscale.
// ---------------------------------------------------------------------------
__global__ __launch_bounds__(256) void conv_all(
    const float* __restrict__ s0, const float* __restrict__ s1,
    const float* __restrict__ s2, const float* __restrict__ s3,
    const float* __restrict__ s4, const float* __restrict__ s5,
    const float* __restrict__ s6, ushort* __restrict__ dst,
    const float* __restrict__ sinp, const float* __restrict__ cosp,
    const float* __restrict__ xscale,
    float2* __restrict__ qt, float2* __restrict__ kt)
{
    if (blockIdx.x >= 14336) {
        const int idx = (blockIdx.x - 14336) * 256 + threadIdx.x;  // 65536
        const int t = idx >> 5;
        const float s = sinp[idx], c = cosp[idx], xs = xscale[idx];
        float sa = 1.f;
        if (t >= 2) {
            const float lv = __logf((float)t) * 0.14426950408889634f; // /ln(1024)
            sa = lv > 1.f ? lv : 1.f;
        }
        const float qs = xs * sa * 0.125f * 1.4426950408889634f;  // * log2(e)
        qt[idx] = make_float2(c * qs, s * qs);
        const float ks = 1.f / xs;
        kt[idx] = make_float2(c * ks, s * ks);
        return;
    }
    const int idx = blockIdx.x * 256 + threadIdx.x;   // 7 * 2^19 threads
    const int t = idx >> 19;
    const int r = (idx & 524287) * 8;
    const float* in = t == 0 ? s0 : t == 1 ? s1 : t == 2 ? s2 : t == 3 ? s3
                    : t == 4 ? s4 : t == 5 ? s5 : s6;
    const float4 v0 = *reinterpret_cast<const float4*>(&in[r]);
    const float4 v1 = *reinterpret_cast<const float4*>(&in[r + 4]);
    ushort o[8];
    o[0] = f2bf(v0.x); o[1] = f2bf(v0.y); o[2] = f2bf(v0.z); o[3] = f2bf(v0.w);
    o[4] = f2bf(v1.x); o[5] = f2bf(v1.y); o[6] = f2bf(v1.z); o[7] = f2bf(v1.w);
    *reinterpret_cast<uint4*>(&dst[(size_t)t * 4194304 + r]) =
        *reinterpret_cast<const uint4*>(o);
}

// ---------------------------------------------------------------------------
// QKV projection, 256x256-tile 8-phase GEMM, 3-slot-A pipeline.
// ROUND-15 CHANGE: 5 barriers/tile instead of 8 — the post-MFMA barrier is
// load-bearing only at ph3 (publishes vmcnt(8)-confirmed A(t+1),B(t+1) to all
// waves). At ph0-2 its orderings are subsumed by the next phase's pre-MFMA
// barrier: B slot t&1 read only at ph0 (ph0's barrier-A orders all reads
// before any wave's ph2 B(t+2) stage); A stages target slot (t+2)%3, never
// the in-tile read slot t%3 nor next tile's (t+1)%3. Waves may now drift one
// phase (MFMA || next phase's ds_reads across waves) — desired overlap.
// ALL slot indices compile-time (round-7 lesson: runtime slots -> spill).
// ---------------------------------------------------------------------------
#define QBM 256
#define QBN 256

#define STAGE_A3(tau, h, slot) do {                                            \
    const int _tc = (tau) * 64;                                                \
    _Pragma("unroll") for (int _i = 0; _i < 2; ++_i) {                         \
        gload_lds16(&Ap[(size_t)(bm + (h) * 128 + wid * 16 + _i * 8 + rl) * 2048 + _tc + csw], \
                    &lds[(slot) * 16384 + (h) * 8192 + (wid * 16 + _i * 8) * 64]); \
    } } while (0)

#define STAGE_B2(tau, h, slot) do {                                            \
    const int _tc = (tau) * 64;                                                \
    _Pragma("unroll") for (int _i = 0; _i < 2; ++_i) {                         \
        gload_lds16(&Bp[(size_t)(bn + (h) * 128 + wid * 16 + _i * 8 + rl) * 2048 + _tc + csw], \
                    &lds[49152 + (slot) * 16384 + (h) * 8192 + (wid * 16 + _i * 8) * 64]); \
    } } while (0)

// one phase: ds-read subtile, issue stage, barrier, prio MFMA cluster,
// optional counted vmcnt, optional end barrier (ph3 only).
#define PH(sa_, sb_, mp, VMWSTMT, ENDBAR, ...) do {                            \
    if ((mp) == 0) {                                                           \
        _Pragma("unroll") for (int n = 0; n < 4; ++n) {                        \
            bf[n][0] = ldB(sb_, n, 0);                                         \
            bf[n][1] = ldB(sb_, n, 1);                                         \
        }                                                                      \
    }                                                                          \
    af[0][0] = ldA(sa_, (mp) * 2, 0);     af[0][1] = ldA(sa_, (mp) * 2, 1);    \
    af[1][0] = ldA(sa_, (mp) * 2 + 1, 0); af[1][1] = ldA(sa_, (mp) * 2 + 1, 1);\
    __VA_ARGS__;                                                               \
    BARRIER();                                                                 \
    __builtin_amdgcn_s_setprio(1);                                             \
    _Pragma("unroll") for (int mm = 0; mm < 2; ++mm)                           \
    _Pragma("unroll") for (int n = 0; n < 4; ++n)                              \
    _Pragma("unroll") for (int kk = 0; kk < 2; ++kk)                           \
        acc[(mp) * 2 + mm][n] = __builtin_amdgcn_mfma_f32_16x16x32_bf16(       \
            af[mm][kk], bf[n][kk], acc[(mp) * 2 + mm][n], 0, 0, 0);            \
    __builtin_amdgcn_s_setprio(0);                                             \
    VMWSTMT;                                                                   \
    ENDBAR;                                                                    \
} while (0)

#define TILE6(sa, sb, sa2, tau2, LASTVMW) do {                                 \
    PH(sa, sb, 0, (void)0, (void)0,   STAGE_A3(tau2, 0, sa2));                 \
    PH(sa, sb, 1, (void)0, (void)0,   STAGE_A3(tau2, 1, sa2));                 \
    PH(sa, sb, 2, (void)0, (void)0,   STAGE_B2(tau2, 0, sb));                  \
    PH(sa, sb, 3, LASTVMW, BARRIER(), STAGE_B2(tau2, 1, sb));                  \
} while (0)

__global__ __launch_bounds__(512, 2) void gemm_qkv8(
    const ushort* __restrict__ Astack,   // [Aq|Ak|Av] bf16, each [2048][2048]
    const ushort* __restrict__ Wstack,   // [Wq|Wk|Wv] bf16, each [2048][2048]
    const float* __restrict__ bq, const float* __restrict__ bk,
    const float* __restrict__ bv,
    ushort* __restrict__ outQ, ushort* __restrict__ outK,
    ushort* __restrict__ outVt,
    const float2* __restrict__ qtab, const float2* __restrict__ ktab)
{
    __shared__ ushort lds[81920];   // 160 KiB: A 3x32KB | B 2x32KB
    const int tid  = threadIdx.x;
    const int lane = tid & 63;
    const int wid  = tid >> 6;      // 0..7

    const int b   = blockIdx.x + blockIdx.y * 24;  // 0..191
    const int xcd = b & 7;
    const int idx = b >> 3;                        // 0..23
    const int bx  = xcd * 3 + (idx >> 3);          // 0..23 col-panel
    const int by  = idx & 7;                       // 0..7  row-panel
    const int which = bx >> 3;                     // 0=Q 1=K 2=V
    const int bn  = (bx & 7) * QBN;
    const int bm  = by * QBM;
    const ushort* Ap = Astack + (size_t)which * 4194304;
    const ushort* Bp = Wstack + (size_t)which * 4194304;

    const int rl  = lane >> 3;
    const int csw = (((lane & 7) ^ ((lane >> 3) & 7)) * 8);
    const int lm  = lane & 15;
    const int lg  = lane >> 4;
    const char* ldsb = reinterpret_cast<const char*>(lds);

    auto ldA = [&](int slot, int m, int kk) -> short8v {
        const int row = m * 16 + lm;
        const int off = (slot * 16384 + (wid >> 2) * 8192) * 2 + row * 128
                      + (((kk * 4 + lg) ^ (row & 7)) * 16);
        return *reinterpret_cast<const short8v*>(ldsb + off);
    };
    auto ldB = [&](int slot, int n, int kk) -> short8v {
        const int row = (wid & 1) * 64 + n * 16 + lm;
        const int off = (49152 + slot * 16384 + ((wid & 3) >> 1) * 8192) * 2
                      + row * 128 + (((kk * 4 + lg) ^ (row & 7)) * 16);
        return *reinterpret_cast<const short8v*>(ldsb + off);
    };

    floatx4 acc[8][4] = {};
    short8v bf[4][2];
    short8v af[2][2];

    STAGE_A3(0, 0, 0); STAGE_A3(0, 1, 0);
    STAGE_B2(0, 0, 0); STAGE_B2(0, 1, 0);
    STAGE_A3(1, 0, 1); STAGE_A3(1, 1, 1);
    STAGE_B2(1, 0, 1); STAGE_B2(1, 1, 1);
    VMW8();
    BARRIER();

    for (int i = 0; i < 5; ++i) {
        const int t = 6 * i;
        TILE6(0, 0, 2, t + 2, VMW8());
        TILE6(1, 1, 0, t + 3, VMW8());
        TILE6(2, 0, 1, t + 4, VMW8());
        TILE6(0, 1, 2, t + 5, VMW8());
        TILE6(1, 0, 0, t + 6, VMW8());
        TILE6(2, 1, 1, t + 7, VMW8());
    }
    // peel t=30 (A s0, B b0): no stages; drain at ph3 then publish.
    PH(0, 0, 0, (void)0, (void)0,   (void)0);
    PH(0, 0, 1, (void)0, (void)0,   (void)0);
    PH(0, 0, 2, (void)0, (void)0,   (void)0);
    PH(0, 0, 3, VMW0(),  BARRIER(), (void)0);
    // peel t=31 (A s1, B b1): nothing outstanding.
    PH(1, 1, 0, (void)0, (void)0, (void)0);
    PH(1, 1, 1, (void)0, (void)0, (void)0);
    PH(1, 1, 2, (void)0, (void)0, (void)0);
    PH(1, 1, 3, (void)0, (void)0, (void)0);

    const float* bias = which == 0 ? bq : which == 1 ? bk : bv;
    const float2* tbl = which == 0 ? qtab : ktab;
    #pragma unroll
    for (int m = 0; m < 8; ++m) {
        #pragma unroll
        for (int n = 0; n < 4; ++n) {
            const int col = bn + (wid & 3) * 64 + n * 16 + lm;
            const float bz = bias[col];
            const int row0 = bm + (wid >> 2) * 128 + m * 16 + lg * 4;
            if (which == 2) {
                ushort o4[4];
                #pragma unroll
                for (int j = 0; j < 4; ++j)
                    o4[j] = f2bf(acc[m][n][j] + bz);
                *reinterpret_cast<uint2*>(&outVt[(size_t)col * T_LEN + row0]) =
                    *reinterpret_cast<const uint2*>(o4);
            } else {
                ushort* O = which == 0 ? outQ : outK;
                const int p = (col & 63) >> 1;
                const bool even = (col & 1) == 0;
                #pragma unroll
                for (int j = 0; j < 4; ++j) {
                    const int row = row0 + j;
                    const float v = acc[m][n][j] + bz;
                    const float pv = __shfl_xor(v, 1);
                    const float2 cs = tbl[row * HALF + p];
                    const float outv = even ? v * cs.x - pv * cs.y
                                            : v * cs.x + pv * cs.y;
                    O[(size_t)row * EMB + col] = f2bf(outv);
                }
            }
        }
    }
}

// ---------------------------------------------------------------------------
// Output projection GEMM, SPLIT-K=2, bf16 partials.
// ---------------------------------------------------------------------------
#define GBM 128
#define GBN 128
#define GBK 64

__global__ __launch_bounds__(256) void gemm_out_sk(
    const ushort* __restrict__ A,
    const ushort* __restrict__ B,
    ushort* __restrict__ P)              // [2][2048][2048] bf16 partials
{
    __shared__ ushort As[GBM * GBK];
    __shared__ ushort Bs[GBN * GBK];
    const int tid  = threadIdx.x;
    const int lane = tid & 63;
    const int wid  = tid >> 6;
    const int bm = blockIdx.y * GBM;
    const int bn = blockIdx.x * GBN;
    const int z  = blockIdx.z;
    const int wr = (wid >> 1) * 64;
    const int wc = (wid & 1) * 64;

    floatx4 acc[4][4] = {};

    const int lrow  = lane >> 3;
    const int lcolb = (lane & 7) * 8;

    for (int k0 = z * 1024; k0 < (z + 1) * 1024; k0 += GBK) {
        #pragma unroll
        for (int c = 0; c < 4; ++c) {
            const int chunk = wid * 4 + c;
            const int row = chunk * 8 + lrow;
            gload_lds16(&A[(size_t)(bm + row) * EMB + k0 + lcolb], &As[chunk * 512]);
            gload_lds16(&B[(size_t)(bn + row) * EMB + k0 + lcolb], &Bs[chunk * 512]);
        }
        __syncthreads();
        #pragma unroll
        for (int kk = 0; kk < 2; ++kk) {
            short8v a[4], b[4];
            #pragma unroll
            for (int m = 0; m < 4; ++m)
                a[m] = *reinterpret_cast<const short8v*>(
                    &As[(wr + m * 16 + (lane & 15)) * GBK + kk * 32 + (lane >> 4) * 8]);
            #pragma unroll
            for (int n = 0; n < 4; ++n)
                b[n] = *reinterpret_cast<const short8v*>(
                    &Bs[(wc + n * 16 + (lane & 15)) * GBK + kk * 32 + (lane >> 4) * 8]);
            #pragma unroll
            for (int m = 0; m < 4; ++m)
                #pragma unroll
                for (int n = 0; n < 4; ++n)
                    acc[m][n] = __builtin_amdgcn_mfma_f32_16x16x32_bf16(
                        a[m], b[n], acc[m][n], 0, 0, 0);
        }
        __syncthreads();
    }

    ushort* Pz = P + (size_t)z * 4194304;
    const int cr = (lane >> 4) * 4;
    const int cc = lane & 15;
    #pragma unroll
    for (int m = 0; m < 4; ++m) {
        #pragma unroll
        for (int n = 0; n < 4; ++n) {
            const int col = bn + wc + n * 16 + cc;
            #pragma unroll
            for (int j = 0; j < 4; ++j) {
                const int row = bm + wr + m * 16 + cr + j;
                Pz[(size_t)row * EMB + col] = f2bf(acc[m][n][j]);
            }
        }
    }
}

// out = P0 + P1 + bias  (bf16 partials -> fp32 out, 8 elem/thread)
__global__ __launch_bounds__(256) void reduce_out(
    const ushort* __restrict__ P, const float* __restrict__ bias,
    float* __restrict__ C)
{
    const int i = (blockIdx.x * 256 + threadIdx.x) * 8;
    const uint4 pa = *reinterpret_cast<const uint4*>(&P[i]);
    const uint4 pb = *reinterpret_cast<const uint4*>(&P[4194304 + i]);
    const ushort* ua = reinterpret_cast<const ushort*>(&pa);
    const ushort* ub = reinterpret_cast<const ushort*>(&pb);
    const int cb = i & 2047;
    float o[8];
    #pragma unroll
    for (int j = 0; j < 8; ++j) {
        union { unsigned u; float f; } fa, fb;
        fa.u = (unsigned)ua[j] << 16;
        fb.u = (unsigned)ub[j] << 16;
        o[j] = fa.f + fb.f + bias[cb + j];
    }
    *reinterpret_cast<float4*>(&C[i])     = make_float4(o[0], o[1], o[2], o[3]);
    *reinterpret_cast<float4*>(&C[i + 4]) = make_float4(o[4], o[5], o[6], o[7]);
}

// ---------------------------------------------------------------------------
// MFMA flash attention — ROUND-12 EXACT kernel (measured ~36 µs; two
// restructure attempts regressed — plateau). 64 q-rows/block, 40 KB LDS,
// 1024 blocks; T5 setprio; tree max/sum; 2-phase pipelined staging;
// defer-max; exp2 (log2e in Q table); cvt_pk P-packing; LPT block order.
// ---------------------------------------------------------------------------
__global__ __launch_bounds__(256) void flash_attn_mfma(
    const ushort* __restrict__ Qb,   // [T][EMB] bf16 (rotary+scaled, log2e)
    const ushort* __restrict__ Kb,   // [T][EMB] bf16 (rotary)
    const ushort* __restrict__ Vt,   // [EMB][T] bf16 (per-head [d][t])
    ushort* __restrict__ Ob)         // [T][EMB] bf16
{
    __shared__ ushort Ks[2][64 * 64];
    __shared__ ushort Vs[2][64 * 64];
    __shared__ ushort Ps[4][16 * 64];

    const int h   = blockIdx.x;
    const int qb  = (T_LEN / 64 - 1) - blockIdx.y;   // LPT: heavy blocks first
    const int tid = threadIdx.x;
    const int lane = tid & 63;
    const int wid  = tid >> 6;
    const int qrow_w = qb * 64 + wid * 16;
    const int lm = lane & 15;
    const int lg = lane >> 4;

    short8v qf[2];
    {
        const ushort* qp = &Qb[(size_t)(qrow_w + lm) * EMB + h * HD + lg * 8];
        qf[0] = *reinterpret_cast<const short8v*>(qp);
        qf[1] = *reinterpret_cast<const short8v*>(qp + 32);
    }

    floatx4 oacc[4] = {};
    float m = -1e30f, l = 0.f;

    const int srow = lane >> 3;
    const int schk = lane & 7;

    {
        #pragma unroll
        for (int i = 0; i < 2; ++i) {
            const int slot = wid * 2 + i;
            const int row  = slot * 8 + srow;
            const int cswz = (schk ^ (row & 7)) * 8;
            gload_lds16(&Kb[(size_t)row * EMB + h * HD + cswz], &Ks[0][slot * 512]);
            gload_lds16(&Vt[(size_t)(h * HD + row) * T_LEN + cswz], &Vs[0][slot * 512]);
        }
    }
    __syncthreads();

    for (int kb = 0; kb <= qb; ++kb) {
        const int cur = kb & 1;
        if (kb < qb) {
            const int nkb = kb + 1;
            #pragma unroll
            for (int i = 0; i < 2; ++i) {
                const int slot = wid * 2 + i;
                const int row  = slot * 8 + srow;
                const int cswz = (schk ^ (row & 7)) * 8;
                gload_lds16(&Kb[(size_t)(nkb * 64 + row) * EMB + h * HD + cswz],
                            &Ks[cur ^ 1][slot * 512]);
                gload_lds16(&Vt[(size_t)(h * HD + row) * T_LEN + nkb * 64 + cswz],
                            &Vs[cur ^ 1][slot * 512]);
            }
        }

        float sv[16];
        __builtin_amdgcn_s_setprio(1);
        #pragma unroll
        for (int t = 0; t < 4; ++t) {
            floatx4 sacc = {};
            const int srow_l = t * 16 + lm;
            const char* krow = reinterpret_cast<const char*>(Ks[cur]) + srow_l * 128;
            const int swz = (srow_l & 7) << 4;
            #pragma unroll
            for (int kk = 0; kk < 2; ++kk) {
                const int cb = (kk * 64 + lg * 16) ^ swz;
                short8v kf = *reinterpret_cast<const short8v*>(krow + cb);
                sacc = __builtin_amdgcn_mfma_f32_16x16x32_bf16(kf, qf[kk], sacc, 0, 0, 0);
            }
            sv[t * 4 + 0] = sacc[0]; sv[t * 4 + 1] = sacc[1];
            sv[t * 4 + 2] = sacc[2]; sv[t * 4 + 3] = sacc[3];
        }
        __builtin_amdgcn_s_setprio(0);

        const int qg = qrow_w + lm;
        if (kb == qb) {
            #pragma unroll
            for (int t = 0; t < 4; ++t)
                #pragma unroll
                for (int r = 0; r < 4; ++r) {
                    const int sg = kb * 64 + t * 16 + lg * 4 + r;
                    if (sg > qg) sv[t * 4 + r] = -1e30f;
                }
        }

        // tree max (depth 4; fmaxf triples fusable to v_max3)
        const float mx0 = fmaxf(fmaxf(fmaxf(sv[0], sv[1]), fmaxf(sv[2], sv[3])),
                                fmaxf(fmaxf(sv[4], sv[5]), fmaxf(sv[6], sv[7])));
        const float mx1 = fmaxf(fmaxf(fmaxf(sv[8], sv[9]), fmaxf(sv[10], sv[11])),
                                fmaxf(fmaxf(sv[12], sv[13]), fmaxf(sv[14], sv[15])));
        float mx = fmaxf(mx0, mx1);
        mx = fmaxf(mx, __shfl_xor(mx, 16));
        mx = fmaxf(mx, __shfl_xor(mx, 32));
        float corr = 1.f;
        if (!__all(mx - m <= 11.544f)) {      // 8 nats in log2 units
            const float mnew = fmaxf(m, mx);
            corr = exp2f(m - mnew);
            m = mnew;
            float corr4[4];
            #pragma unroll
            for (int r = 0; r < 4; ++r)
                corr4[r] = __shfl(corr, lg * 4 + r);
            #pragma unroll
            for (int td = 0; td < 4; ++td)
                #pragma unroll
                for (int r = 0; r < 4; ++r)
                    oacc[td][r] *= corr4[r];
        }
        float psum[8];
        unsigned pw[8];
        #pragma unroll
        for (int i = 0; i < 8; ++i) {
            const float p0 = exp2f(sv[2 * i + 0] - m);
            const float p1 = exp2f(sv[2 * i + 1] - m);
            psum[i] = p0 + p1;
            const __hip_bfloat162 h2 = __float22bfloat162_rn(make_float2(p0, p1));
            pw[i] = *reinterpret_cast<const unsigned*>(&h2);
        }
        float ps = ((psum[0] + psum[1]) + (psum[2] + psum[3]))
                 + ((psum[4] + psum[5]) + (psum[6] + psum[7]));
        ps += __shfl_xor(ps, 16);
        ps += __shfl_xor(ps, 32);
        l = l * corr + ps;

        {
            char* pbase = reinterpret_cast<char*>(&Ps[wid][0]) + lm * 128;
            const int swz = (lm & 7) << 4;
            #pragma unroll
            for (int t = 0; t < 4; ++t) {
                uint2 w;
                w.x = pw[2 * t + 0];
                w.y = pw[2 * t + 1];
                const int cb = (t * 32 + lg * 8) ^ swz;
                *reinterpret_cast<uint2*>(pbase + cb) = w;
            }
        }

        const char* pwave = reinterpret_cast<const char*>(&Ps[wid][0]);
        __builtin_amdgcn_s_setprio(1);
        #pragma unroll
        for (int kk = 0; kk < 2; ++kk) {
            const int acb = (kk * 64 + lg * 16) ^ ((lm & 7) << 4);
            short8v pa = *reinterpret_cast<const short8v*>(pwave + lm * 128 + acb);
            #pragma unroll
            for (int td = 0; td < 4; ++td) {
                const int d = td * 16 + lm;
                const int bcb = (kk * 64 + lg * 16) ^ ((d & 7) << 4);
                short8v vb = *reinterpret_cast<const short8v*>(
                    reinterpret_cast<const char*>(Vs[cur]) + d * 128 + bcb);
                oacc[td] = __builtin_amdgcn_mfma_f32_16x16x32_bf16(pa, vb, oacc[td], 0, 0, 0);
            }
        }
        __builtin_amdgcn_s_setprio(0);

        __syncthreads();
    }

    float invl[4];
    #pragma unroll
    for (int r = 0; r < 4; ++r)
        invl[r] = 1.f / __shfl(l, lg * 4 + r);
    #pragma unroll
    for (int td = 0; td < 4; ++td) {
        #pragma unroll
        for (int r = 0; r < 4; ++r) {
            const int trow = qrow_w + lg * 4 + r;
            const int col  = h * HD + td * 16 + lm;
            Ob[(size_t)trow * EMB + col] = f2bf(oacc[td][r] * invl[r]);
        }
    }
}

// ---------------------------------------------------------------------------
// Launch. 5 dispatches. Workspace (90 MB):
//   +0  [Wq|Wk|Wv] bf16 (24MB stacked)  +24 bWo
//   +32 [bAq|bAk|bAv] bf16 (24MB; dead after qkv8 -> bf16 partials 16MB)
//   +56 bQ   +64 bK   +72 bVt  +80 bAo   +88 qtab (512KB)  +88.5 ktab (512KB)
// ---------------------------------------------------------------------------
extern "C" void kernel_launch(void* const* d_in, const int* in_sizes, int n_in,
                              void* d_out, int out_size, void* d_ws, size_t ws_size,
                              hipStream_t stream) {
    const float* query = (const float*)d_in[0];
    const float* key   = (const float*)d_in[1];
    const float* value = (const float*)d_in[2];
    const float* Wq = (const float*)d_in[3];
    const float* bq = (const float*)d_in[4];
    const float* Wk = (const float*)d_in[5];
    const float* bk = (const float*)d_in[6];
    const float* Wv = (const float*)d_in[7];
    const float* bv = (const float*)d_in[8];
    const float* Wo = (const float*)d_in[9];
    const float* bo = (const float*)d_in[10];
    const float* sinp   = (const float*)d_in[11];
    const float* cosp   = (const float*)d_in[12];
    const float* xscale = (const float*)d_in[13];
    float* out = (float*)d_out;

    const size_t MB = 1024 * 1024;
    char* ws = (char*)d_ws;
    ushort* bWqkv = (ushort*)(ws + 0 * MB);
    ushort* bWo   = (ushort*)(ws + 24 * MB);
    ushort* bAqkv = (ushort*)(ws + 32 * MB);
    ushort* bQ  = (ushort*)(ws + 56 * MB);
    ushort* bK  = (ushort*)(ws + 64 * MB);
    ushort* bVt = (ushort*)(ws + 72 * MB);
    ushort* bAo = (ushort*)(ws + 80 * MB);
    float2* qtab = (float2*)(ws + 88 * MB);
    float2* ktab = (float2*)(ws + 88 * MB + 512 * 1024);
    ushort* Pout = (ushort*)(ws + 32 * MB);  // 16MB bf16 partials (overlay)

    conv_all<<<14336 + 256, 256, 0, stream>>>(
        Wq, Wk, Wv, Wo, query, key, value, bWqkv,
        sinp, cosp, xscale, qtab, ktab);

    dim3 gQKV(24, 8);                          // 192 blocks, 512 thr
    gemm_qkv8<<<gQKV, 512, 0, stream>>>(bAqkv, bWqkv, bq, bk, bv,
                                        bQ, bK, bVt, qtab, ktab);

    dim3 gFlash(NH, T_LEN / 64);               // 1024 blocks, 64 q-rows each
    flash_attn_mfma<<<gFlash, 256, 0, stream>>>(bQ, bK, bVt, bAo);

    dim3 gOut(EMB / GBN, T_LEN / GBM, 2);      // split-K=2: 512 blocks
    gemm_out_sk<<<gOut, 256, 0, stream>>>(bAo, bWo, Pout);
    reduce_out<<<T_LEN * EMB / (256 * 8), 256, 0, stream>>>(Pout, bo, out);
}

// Round 16
// 167.483 us; speedup vs baseline: 1.2156x; 1.0074x over previous
//
#include <hip/hip_runtime.h>
#include <hip/hip_bf16.h>
#include <math.h>

// Problem constants (fixed by harness)
#define T_LEN 2048
#define EMB   2048
#define NH    32
#define HD    64
#define HALF  32

typedef __attribute__((ext_vector_type(8))) short short8v;   // 8 bf16 (4 VGPR)
typedef __attribute__((ext_vector_type(4))) float floatx4;   // MFMA C/D

// async global->LDS, 16B per lane. LDS dest is wave-uniform base + lane*16.
__device__ inline void gload_lds16(const void* g, void* l) {
    __builtin_amdgcn_global_load_lds(
        (const __attribute__((address_space(1))) unsigned int*)g,
        (__attribute__((address_space(3))) unsigned int*)l,
        16, 0, 0);
}

__device__ inline ushort f2bf(float x) {
    union { float f; unsigned u; } c; c.f = x;
    const unsigned r = c.u + 0x7FFFu + ((c.u >> 16) & 1u);  // RNE
    return (ushort)(r >> 16);
}

// raw barrier with compiler memory fences (NO vmcnt drain, unlike __syncthreads)
#define BARRIER() do { asm volatile("" ::: "memory"); \
    __builtin_amdgcn_s_barrier(); asm volatile("" ::: "memory"); } while (0)
#define VMW8() asm volatile("s_waitcnt vmcnt(8)" ::: "memory")
#define VMW0() asm volatile("s_waitcnt vmcnt(0)" ::: "memory")

// ---------------------------------------------------------------------------
// Fused: fp32->bf16 conversion of all 7 tensors (blocks 0..14335) + rotary
// coefficient tables (blocks 14336..14591). Q table folds xscale *
// scale_attention * HD^-0.5 * log2(e); K table = 1/xscale.
// ---------------------------------------------------------------------------
__global__ __launch_bounds__(256) void conv_all(
    const float* __restrict__ s0, const float* __restrict__ s1,
    const float* __restrict__ s2, const float* __restrict__ s3,
    const float* __restrict__ s4, const float* __restrict__ s5,
    const float* __restrict__ s6, ushort* __restrict__ dst,
    const float* __restrict__ sinp, const float* __restrict__ cosp,
    const float* __restrict__ xscale,
    float2* __restrict__ qt, float2* __restrict__ kt)
{
    if (blockIdx.x >= 14336) {
        const int idx = (blockIdx.x - 14336) * 256 + threadIdx.x;  // 65536
        const int t = idx >> 5;
        const float s = sinp[idx], c = cosp[idx], xs = xscale[idx];
        float sa = 1.f;
        if (t >= 2) {
            const float lv = __logf((float)t) * 0.14426950408889634f; // /ln(1024)
            sa = lv > 1.f ? lv : 1.f;
        }
        const float qs = xs * sa * 0.125f * 1.4426950408889634f;  // * log2(e)
        qt[idx] = make_float2(c * qs, s * qs);
        const float ks = 1.f / xs;
        kt[idx] = make_float2(c * ks, s * ks);
        return;
    }
    const int idx = blockIdx.x * 256 + threadIdx.x;   // 7 * 2^19 threads
    const int t = idx >> 19;
    const int r = (idx & 524287) * 8;
    const float* in = t == 0 ? s0 : t == 1 ? s1 : t == 2 ? s2 : t == 3 ? s3
                    : t == 4 ? s4 : t == 5 ? s5 : s6;
    const float4 v0 = *reinterpret_cast<const float4*>(&in[r]);
    const float4 v1 = *reinterpret_cast<const float4*>(&in[r + 4]);
    ushort o[8];
    o[0] = f2bf(v0.x); o[1] = f2bf(v0.y); o[2] = f2bf(v0.z); o[3] = f2bf(v0.w);
    o[4] = f2bf(v1.x); o[5] = f2bf(v1.y); o[6] = f2bf(v1.z); o[7] = f2bf(v1.w);
    *reinterpret_cast<uint4*>(&dst[(size_t)t * 4194304 + r]) =
        *reinterpret_cast<const uint4*>(o);
}

// ---------------------------------------------------------------------------
// QKV projection, 256x256-tile 8-phase GEMM, 3-slot-A pipeline.
// ROUND-16: 2 barriers/tile (was 5; was 8 in round 14 — each step measured).
// Ledger (verified under maximal wave drift):
//   ph1-pre barrier: the ONLY protector of the B WAR — ph0's B-frag reads
//     are consumed by ph0's MFMA (compiler lgkmcnt) before any wave reaches
//     ph1-pre; B(t+2) stages into the same slot are issued after ph1-pre.
//   ph3-end barrier (after per-wave VMW8): publishes A(t+1),B(t+1) to all
//     waves; orders tile-t A-slot reads before tile-(t+1)'s A(t+3) stage.
//   ph0/ph2/ph3 pre-barriers: redundant (orderings subsumed by the above).
// ALL slot indices compile-time (round-7 lesson: runtime slots -> spill).
// ---------------------------------------------------------------------------
#define QBM 256
#define QBN 256

#define STAGE_A3(tau, h, slot) do {                                            \
    const int _tc = (tau) * 64;                                                \
    _Pragma("unroll") for (int _i = 0; _i < 2; ++_i) {                         \
        gload_lds16(&Ap[(size_t)(bm + (h) * 128 + wid * 16 + _i * 8 + rl) * 2048 + _tc + csw], \
                    &lds[(slot) * 16384 + (h) * 8192 + (wid * 16 + _i * 8) * 64]); \
    } } while (0)

#define STAGE_B2(tau, h, slot) do {                                            \
    const int _tc = (tau) * 64;                                                \
    _Pragma("unroll") for (int _i = 0; _i < 2; ++_i) {                         \
        gload_lds16(&Bp[(size_t)(bn + (h) * 128 + wid * 16 + _i * 8 + rl) * 2048 + _tc + csw], \
                    &lds[49152 + (slot) * 16384 + (h) * 8192 + (wid * 16 + _i * 8) * 64]); \
    } } while (0)

// one phase: ds-read subtile, issue stage, optional pre-barrier, prio MFMA
// cluster, optional counted vmcnt, optional end barrier.
#define PH(sa_, sb_, mp, VMWSTMT, PREBAR, ENDBAR, ...) do {                    \
    if ((mp) == 0) {                                                           \
        _Pragma("unroll") for (int n = 0; n < 4; ++n) {                        \
            bf[n][0] = ldB(sb_, n, 0);                                         \
            bf[n][1] = ldB(sb_, n, 1);                                         \
        }                                                                      \
    }                                                                          \
    af[0][0] = ldA(sa_, (mp) * 2, 0);     af[0][1] = ldA(sa_, (mp) * 2, 1);    \
    af[1][0] = ldA(sa_, (mp) * 2 + 1, 0); af[1][1] = ldA(sa_, (mp) * 2 + 1, 1);\
    __VA_ARGS__;                                                               \
    PREBAR;                                                                    \
    __builtin_amdgcn_s_setprio(1);                                             \
    _Pragma("unroll") for (int mm = 0; mm < 2; ++mm)                           \
    _Pragma("unroll") for (int n = 0; n < 4; ++n)                              \
    _Pragma("unroll") for (int kk = 0; kk < 2; ++kk)                           \
        acc[(mp) * 2 + mm][n] = __builtin_amdgcn_mfma_f32_16x16x32_bf16(       \
            af[mm][kk], bf[n][kk], acc[(mp) * 2 + mm][n], 0, 0, 0);            \
    __builtin_amdgcn_s_setprio(0);                                             \
    VMWSTMT;                                                                   \
    ENDBAR;                                                                    \
} while (0)

#define TILE6(sa, sb, sa2, tau2, LASTVMW) do {                                 \
    PH(sa, sb, 0, (void)0, (void)0,   (void)0,   STAGE_A3(tau2, 0, sa2));      \
    PH(sa, sb, 1, (void)0, BARRIER(), (void)0,   STAGE_A3(tau2, 1, sa2));      \
    PH(sa, sb, 2, (void)0, (void)0,   (void)0,   STAGE_B2(tau2, 0, sb));       \
    PH(sa, sb, 3, LASTVMW, (void)0,   BARRIER(), STAGE_B2(tau2, 1, sb));       \
} while (0)

__global__ __launch_bounds__(512, 2) void gemm_qkv8(
    const ushort* __restrict__ Astack,   // [Aq|Ak|Av] bf16, each [2048][2048]
    const ushort* __restrict__ Wstack,   // [Wq|Wk|Wv] bf16, each [2048][2048]
    const float* __restrict__ bq, const float* __restrict__ bk,
    const float* __restrict__ bv,
    ushort* __restrict__ outQ, ushort* __restrict__ outK,
    ushort* __restrict__ outVt,
    const float2* __restrict__ qtab, const float2* __restrict__ ktab)
{
    __shared__ ushort lds[81920];   // 160 KiB: A 3x32KB | B 2x32KB
    const int tid  = threadIdx.x;
    const int lane = tid & 63;
    const int wid  = tid >> 6;      // 0..7

    const int b   = blockIdx.x + blockIdx.y * 24;  // 0..191
    const int xcd = b & 7;
    const int idx = b >> 3;                        // 0..23
    const int bx  = xcd * 3 + (idx >> 3);          // 0..23 col-panel
    const int by  = idx & 7;                       // 0..7  row-panel
    const int which = bx >> 3;                     // 0=Q 1=K 2=V
    const int bn  = (bx & 7) * QBN;
    const int bm  = by * QBM;
    const ushort* Ap = Astack + (size_t)which * 4194304;
    const ushort* Bp = Wstack + (size_t)which * 4194304;

    const int rl  = lane >> 3;
    const int csw = (((lane & 7) ^ ((lane >> 3) & 7)) * 8);
    const int lm  = lane & 15;
    const int lg  = lane >> 4;
    const char* ldsb = reinterpret_cast<const char*>(lds);

    auto ldA = [&](int slot, int m, int kk) -> short8v {
        const int row = m * 16 + lm;
        const int off = (slot * 16384 + (wid >> 2) * 8192) * 2 + row * 128
                      + (((kk * 4 + lg) ^ (row & 7)) * 16);
        return *reinterpret_cast<const short8v*>(ldsb + off);
    };
    auto ldB = [&](int slot, int n, int kk) -> short8v {
        const int row = (wid & 1) * 64 + n * 16 + lm;
        const int off = (49152 + slot * 16384 + ((wid & 3) >> 1) * 8192) * 2
                      + row * 128 + (((kk * 4 + lg) ^ (row & 7)) * 16);
        return *reinterpret_cast<const short8v*>(ldsb + off);
    };

    floatx4 acc[8][4] = {};
    short8v bf[4][2];
    short8v af[2][2];

    STAGE_A3(0, 0, 0); STAGE_A3(0, 1, 0);
    STAGE_B2(0, 0, 0); STAGE_B2(0, 1, 0);
    STAGE_A3(1, 0, 1); STAGE_A3(1, 1, 1);
    STAGE_B2(1, 0, 1); STAGE_B2(1, 1, 1);
    VMW8();
    BARRIER();

    for (int i = 0; i < 5; ++i) {
        const int t = 6 * i;
        TILE6(0, 0, 2, t + 2, VMW8());
        TILE6(1, 1, 0, t + 3, VMW8());
        TILE6(2, 0, 1, t + 4, VMW8());
        TILE6(0, 1, 2, t + 5, VMW8());
        TILE6(1, 0, 0, t + 6, VMW8());
        TILE6(2, 1, 1, t + 7, VMW8());
    }
    // peel t=30 (A s0, B b0): no stages; drain A(31),B(31) at ph3, publish.
    PH(0, 0, 0, (void)0, (void)0,   (void)0,   (void)0);
    PH(0, 0, 1, (void)0, (void)0,   (void)0,   (void)0);
    PH(0, 0, 2, (void)0, (void)0,   (void)0,   (void)0);
    PH(0, 0, 3, VMW0(),  (void)0,   BARRIER(), (void)0);
    // peel t=31 (A s1, B b1): nothing outstanding, no hazards after.
    PH(1, 1, 0, (void)0, (void)0, (void)0, (void)0);
    PH(1, 1, 1, (void)0, (void)0, (void)0, (void)0);
    PH(1, 1, 2, (void)0, (void)0, (void)0, (void)0);
    PH(1, 1, 3, (void)0, (void)0, (void)0, (void)0);

    const float* bias = which == 0 ? bq : which == 1 ? bk : bv;
    const float2* tbl = which == 0 ? qtab : ktab;
    #pragma unroll
    for (int m = 0; m < 8; ++m) {
        #pragma unroll
        for (int n = 0; n < 4; ++n) {
            const int col = bn + (wid & 3) * 64 + n * 16 + lm;
            const float bz = bias[col];
            const int row0 = bm + (wid >> 2) * 128 + m * 16 + lg * 4;
            if (which == 2) {
                ushort o4[4];
                #pragma unroll
                for (int j = 0; j < 4; ++j)
                    o4[j] = f2bf(acc[m][n][j] + bz);
                *reinterpret_cast<uint2*>(&outVt[(size_t)col * T_LEN + row0]) =
                    *reinterpret_cast<const uint2*>(o4);
            } else {
                ushort* O = which == 0 ? outQ : outK;
                const int p = (col & 63) >> 1;
                const bool even = (col & 1) == 0;
                #pragma unroll
                for (int j = 0; j < 4; ++j) {
                    const int row = row0 + j;
                    const float v = acc[m][n][j] + bz;
                    const float pv = __shfl_xor(v, 1);
                    const float2 cs = tbl[row * HALF + p];
                    const float outv = even ? v * cs.x - pv * cs.y
                                            : v * cs.x + pv * cs.y;
                    O[(size_t)row * EMB + col] = f2bf(outv);
                }
            }
        }
    }
}

// ---------------------------------------------------------------------------
// Output projection GEMM, SPLIT-K=2, bf16 partials.
// ---------------------------------------------------------------------------
#define GBM 128
#define GBN 128
#define GBK 64

__global__ __launch_bounds__(256) void gemm_out_sk(
    const ushort* __restrict__ A,
    const ushort* __restrict__ B,
    ushort* __restrict__ P)              // [2][2048][2048] bf16 partials
{
    __shared__ ushort As[GBM * GBK];
    __shared__ ushort Bs[GBN * GBK];
    const int tid  = threadIdx.x;
    const int lane = tid & 63;
    const int wid  = tid >> 6;
    const int bm = blockIdx.y * GBM;
    const int bn = blockIdx.x * GBN;
    const int z  = blockIdx.z;
    const int wr = (wid >> 1) * 64;
    const int wc = (wid & 1) * 64;

    floatx4 acc[4][4] = {};

    const int lrow  = lane >> 3;
    const int lcolb = (lane & 7) * 8;

    for (int k0 = z * 1024; k0 < (z + 1) * 1024; k0 += GBK) {
        #pragma unroll
        for (int c = 0; c < 4; ++c) {
            const int chunk = wid * 4 + c;
            const int row = chunk * 8 + lrow;
            gload_lds16(&A[(size_t)(bm + row) * EMB + k0 + lcolb], &As[chunk * 512]);
            gload_lds16(&B[(size_t)(bn + row) * EMB + k0 + lcolb], &Bs[chunk * 512]);
        }
        __syncthreads();
        #pragma unroll
        for (int kk = 0; kk < 2; ++kk) {
            short8v a[4], b[4];
            #pragma unroll
            for (int m = 0; m < 4; ++m)
                a[m] = *reinterpret_cast<const short8v*>(
                    &As[(wr + m * 16 + (lane & 15)) * GBK + kk * 32 + (lane >> 4) * 8]);
            #pragma unroll
            for (int n = 0; n < 4; ++n)
                b[n] = *reinterpret_cast<const short8v*>(
                    &Bs[(wc + n * 16 + (lane & 15)) * GBK + kk * 32 + (lane >> 4) * 8]);
            #pragma unroll
            for (int m = 0; m < 4; ++m)
                #pragma unroll
                for (int n = 0; n < 4; ++n)
                    acc[m][n] = __builtin_amdgcn_mfma_f32_16x16x32_bf16(
                        a[m], b[n], acc[m][n], 0, 0, 0);
        }
        __syncthreads();
    }

    ushort* Pz = P + (size_t)z * 4194304;
    const int cr = (lane >> 4) * 4;
    const int cc = lane & 15;
    #pragma unroll
    for (int m = 0; m < 4; ++m) {
        #pragma unroll
        for (int n = 0; n < 4; ++n) {
            const int col = bn + wc + n * 16 + cc;
            #pragma unroll
            for (int j = 0; j < 4; ++j) {
                const int row = bm + wr + m * 16 + cr + j;
                Pz[(size_t)row * EMB + col] = f2bf(acc[m][n][j]);
            }
        }
    }
}

// out = P0 + P1 + bias  (bf16 partials -> fp32 out, 8 elem/thread)
__global__ __launch_bounds__(256) void reduce_out(
    const ushort* __restrict__ P, const float* __restrict__ bias,
    float* __restrict__ C)
{
    const int i = (blockIdx.x * 256 + threadIdx.x) * 8;
    const uint4 pa = *reinterpret_cast<const uint4*>(&P[i]);
    const uint4 pb = *reinterpret_cast<const uint4*>(&P[4194304 + i]);
    const ushort* ua = reinterpret_cast<const ushort*>(&pa);
    const ushort* ub = reinterpret_cast<const ushort*>(&pb);
    const int cb = i & 2047;
    float o[8];
    #pragma unroll
    for (int j = 0; j < 8; ++j) {
        union { unsigned u; float f; } fa, fb;
        fa.u = (unsigned)ua[j] << 16;
        fb.u = (unsigned)ub[j] << 16;
        o[j] = fa.f + fb.f + bias[cb + j];
    }
    *reinterpret_cast<float4*>(&C[i])     = make_float4(o[0], o[1], o[2], o[3]);
    *reinterpret_cast<float4*>(&C[i + 4]) = make_float4(o[4], o[5], o[6], o[7]);
}

// ---------------------------------------------------------------------------
// MFMA flash attention — ROUND-12 EXACT kernel (measured ~36 µs; two
// restructure attempts regressed — plateau). 64 q-rows/block, 40 KB LDS,
// 1024 blocks; T5 setprio; tree max/sum; 2-phase pipelined staging;
// defer-max; exp2 (log2e in Q table); cvt_pk P-packing; LPT block order.
// ---------------------------------------------------------------------------
__global__ __launch_bounds__(256) void flash_attn_mfma(
    const ushort* __restrict__ Qb,   // [T][EMB] bf16 (rotary+scaled, log2e)
    const ushort* __restrict__ Kb,   // [T][EMB] bf16 (rotary)
    const ushort* __restrict__ Vt,   // [EMB][T] bf16 (per-head [d][t])
    ushort* __restrict__ Ob)         // [T][EMB] bf16
{
    __shared__ ushort Ks[2][64 * 64];
    __shared__ ushort Vs[2][64 * 64];
    __shared__ ushort Ps[4][16 * 64];

    const int h   = blockIdx.x;
    const int qb  = (T_LEN / 64 - 1) - blockIdx.y;   // LPT: heavy blocks first
    const int tid = threadIdx.x;
    const int lane = tid & 63;
    const int wid  = tid >> 6;
    const int qrow_w = qb * 64 + wid * 16;
    const int lm = lane & 15;
    const int lg = lane >> 4;

    short8v qf[2];
    {
        const ushort* qp = &Qb[(size_t)(qrow_w + lm) * EMB + h * HD + lg * 8];
        qf[0] = *reinterpret_cast<const short8v*>(qp);
        qf[1] = *reinterpret_cast<const short8v*>(qp + 32);
    }

    floatx4 oacc[4] = {};
    float m = -1e30f, l = 0.f;

    const int srow = lane >> 3;
    const int schk = lane & 7;

    {
        #pragma unroll
        for (int i = 0; i < 2; ++i) {
            const int slot = wid * 2 + i;
            const int row  = slot * 8 + srow;
            const int cswz = (schk ^ (row & 7)) * 8;
            gload_lds16(&Kb[(size_t)row * EMB + h * HD + cswz], &Ks[0][slot * 512]);
            gload_lds16(&Vt[(size_t)(h * HD + row) * T_LEN + cswz], &Vs[0][slot * 512]);
        }
    }
    __syncthreads();

    for (int kb = 0; kb <= qb; ++kb) {
        const int cur = kb & 1;
        if (kb < qb) {
            const int nkb = kb + 1;
            #pragma unroll
            for (int i = 0; i < 2; ++i) {
                const int slot = wid * 2 + i;
                const int row  = slot * 8 + srow;
                const int cswz = (schk ^ (row & 7)) * 8;
                gload_lds16(&Kb[(size_t)(nkb * 64 + row) * EMB + h * HD + cswz],
                            &Ks[cur ^ 1][slot * 512]);
                gload_lds16(&Vt[(size_t)(h * HD + row) * T_LEN + nkb * 64 + cswz],
                            &Vs[cur ^ 1][slot * 512]);
            }
        }

        float sv[16];
        __builtin_amdgcn_s_setprio(1);
        #pragma unroll
        for (int t = 0; t < 4; ++t) {
            floatx4 sacc = {};
            const int srow_l = t * 16 + lm;
            const char* krow = reinterpret_cast<const char*>(Ks[cur]) + srow_l * 128;
            const int swz = (srow_l & 7) << 4;
            #pragma unroll
            for (int kk = 0; kk < 2; ++kk) {
                const int cb = (kk * 64 + lg * 16) ^ swz;
                short8v kf = *reinterpret_cast<const short8v*>(krow + cb);
                sacc = __builtin_amdgcn_mfma_f32_16x16x32_bf16(kf, qf[kk], sacc, 0, 0, 0);
            }
            sv[t * 4 + 0] = sacc[0]; sv[t * 4 + 1] = sacc[1];
            sv[t * 4 + 2] = sacc[2]; sv[t * 4 + 3] = sacc[3];
        }
        __builtin_amdgcn_s_setprio(0);

        const int qg = qrow_w + lm;
        if (kb == qb) {
            #pragma unroll
            for (int t = 0; t < 4; ++t)
                #pragma unroll
                for (int r = 0; r < 4; ++r) {
                    const int sg = kb * 64 + t * 16 + lg * 4 + r;
                    if (sg > qg) sv[t * 4 + r] = -1e30f;
                }
        }

        // tree max (depth 4; fmaxf triples fusable to v_max3)
        const float mx0 = fmaxf(fmaxf(fmaxf(sv[0], sv[1]), fmaxf(sv[2], sv[3])),
                                fmaxf(fmaxf(sv[4], sv[5]), fmaxf(sv[6], sv[7])));
        const float mx1 = fmaxf(fmaxf(fmaxf(sv[8], sv[9]), fmaxf(sv[10], sv[11])),
                                fmaxf(fmaxf(sv[12], sv[13]), fmaxf(sv[14], sv[15])));
        float mx = fmaxf(mx0, mx1);
        mx = fmaxf(mx, __shfl_xor(mx, 16));
        mx = fmaxf(mx, __shfl_xor(mx, 32));
        float corr = 1.f;
        if (!__all(mx - m <= 11.544f)) {      // 8 nats in log2 units
            const float mnew = fmaxf(m, mx);
            corr = exp2f(m - mnew);
            m = mnew;
            float corr4[4];
            #pragma unroll
            for (int r = 0; r < 4; ++r)
                corr4[r] = __shfl(corr, lg * 4 + r);
            #pragma unroll
            for (int td = 0; td < 4; ++td)
                #pragma unroll
                for (int r = 0; r < 4; ++r)
                    oacc[td][r] *= corr4[r];
        }
        float psum[8];
        unsigned pw[8];
        #pragma unroll
        for (int i = 0; i < 8; ++i) {
            const float p0 = exp2f(sv[2 * i + 0] - m);
            const float p1 = exp2f(sv[2 * i + 1] - m);
            psum[i] = p0 + p1;
            const __hip_bfloat162 h2 = __float22bfloat162_rn(make_float2(p0, p1));
            pw[i] = *reinterpret_cast<const unsigned*>(&h2);
        }
        float ps = ((psum[0] + psum[1]) + (psum[2] + psum[3]))
                 + ((psum[4] + psum[5]) + (psum[6] + psum[7]));
        ps += __shfl_xor(ps, 16);
        ps += __shfl_xor(ps, 32);
        l = l * corr + ps;

        {
            char* pbase = reinterpret_cast<char*>(&Ps[wid][0]) + lm * 128;
            const int swz = (lm & 7) << 4;
            #pragma unroll
            for (int t = 0; t < 4; ++t) {
                uint2 w;
                w.x = pw[2 * t + 0];
                w.y = pw[2 * t + 1];
                const int cb = (t * 32 + lg * 8) ^ swz;
                *reinterpret_cast<uint2*>(pbase + cb) = w;
            }
        }

        const char* pwave = reinterpret_cast<const char*>(&Ps[wid][0]);
        __builtin_amdgcn_s_setprio(1);
        #pragma unroll
        for (int kk = 0; kk < 2; ++kk) {
            const int acb = (kk * 64 + lg * 16) ^ ((lm & 7) << 4);
            short8v pa = *reinterpret_cast<const short8v*>(pwave + lm * 128 + acb);
            #pragma unroll
            for (int td = 0; td < 4; ++td) {
                const int d = td * 16 + lm;
                const int bcb = (kk * 64 + lg * 16) ^ ((d & 7) << 4);
                short8v vb = *reinterpret_cast<const short8v*>(
                    reinterpret_cast<const char*>(Vs[cur]) + d * 128 + bcb);
                oacc[td] = __builtin_amdgcn_mfma_f32_16x16x32_bf16(pa, vb, oacc[td], 0, 0, 0);
            }
        }
        __builtin_amdgcn_s_setprio(0);

        __syncthreads();
    }

    float invl[4];
    #pragma unroll
    for (int r = 0; r < 4; ++r)
        invl[r] = 1.f / __shfl(l, lg * 4 + r);
    #pragma unroll
    for (int td = 0; td < 4; ++td) {
        #pragma unroll
        for (int r = 0; r < 4; ++r) {
            const int trow = qrow_w + lg * 4 + r;
            const int col  = h * HD + td * 16 + lm;
            Ob[(size_t)trow * EMB + col] = f2bf(oacc[td][r] * invl[r]);
        }
    }
}

// ---------------------------------------------------------------------------
// Launch. 5 dispatches. Workspace (90 MB):
//   +0  [Wq|Wk|Wv] bf16 (24MB stacked)  +24 bWo
//   +32 [bAq|bAk|bAv] bf16 (24MB; dead after qkv8 -> bf16 partials 16MB)
//   +56 bQ   +64 bK   +72 bVt  +80 bAo   +88 qtab (512KB)  +88.5 ktab (512KB)
// ---------------------------------------------------------------------------
extern "C" void kernel_launch(void* const* d_in, const int* in_sizes, int n_in,
                              void* d_out, int out_size, void* d_ws, size_t ws_size,
                              hipStream_t stream) {
    const float* query = (const float*)d_in[0];
    const float* key   = (const float*)d_in[1];
    const float* value = (const float*)d_in[2];
    const float* Wq = (const float*)d_in[3];
    const float* bq = (const float*)d_in[4];
    const float* Wk = (const float*)d_in[5];
    const float* bk = (const float*)d_in[6];
    const float* Wv = (const float*)d_in[7];
    const float* bv = (const float*)d_in[8];
    const float* Wo = (const float*)d_in[9];
    const float* bo = (const float*)d_in[10];
    const float* sinp   = (const float*)d_in[11];
    const float* cosp   = (const float*)d_in[12];
    const float* xscale = (const float*)d_in[13];
    float* out = (float*)d_out;

    const size_t MB = 1024 * 1024;
    char* ws = (char*)d_ws;
    ushort* bWqkv = (ushort*)(ws + 0 * MB);
    ushort* bWo   = (ushort*)(ws + 24 * MB);
    ushort* bAqkv = (ushort*)(ws + 32 * MB);
    ushort* bQ  = (ushort*)(ws + 56 * MB);
    ushort* bK  = (ushort*)(ws + 64 * MB);
    ushort* bVt = (ushort*)(ws + 72 * MB);
    ushort* bAo = (ushort*)(ws + 80 * MB);
    float2* qtab = (float2*)(ws + 88 * MB);
    float2* ktab = (float2*)(ws + 88 * MB + 512 * 1024);
    ushort* Pout = (ushort*)(ws + 32 * MB);  // 16MB bf16 partials (overlay)

    conv_all<<<14336 + 256, 256, 0, stream>>>(
        Wq, Wk, Wv, Wo, query, key, value, bWqkv,
        sinp, cosp, xscale, qtab, ktab);

    dim3 gQKV(24, 8);                          // 192 blocks, 512 thr
    gemm_qkv8<<<gQKV, 512, 0, stream>>>(bAqkv, bWqkv, bq, bk, bv,
                                        bQ, bK, bVt, qtab, ktab);

    dim3 gFlash(NH, T_LEN / 64);               // 1024 blocks, 64 q-rows each
    flash_attn_mfma<<<gFlash, 256, 0, stream>>>(bQ, bK, bVt, bAo);

    dim3 gOut(EMB / GBN, T_LEN / GBM, 2);      // split-K=2: 512 blocks
    gemm_out_sk<<<gOut, 256, 0, stream>>>(bAo, bWo, Pout);
    reduce_out<<<T_LEN * EMB / (256 * 8), 256, 0, stream>>>(Pout, bo, out);
}